// Round 4
// baseline (354.520 us; speedup 1.0000x reference)
//
#include <hip/hip_runtime.h>
#include <cstdint>
#include <cstddef>

// Problem constants (fixed by reference shapes)
#define T_    4
#define B_    2
#define NW_   64
#define WS_   128
#define C_    256
#define NC3   768
#define H_    8
#define HD_   32
#define TOPK_ 4
#define RCAP  131072
#define BAND  0.008f
#define RBCAP 512          // per-block LDS rescue staging capacity (per p-pass)

// Workspace layout (bytes, all 16B aligned). Total ~92.7 MB.
// A2/Bq/Bp are stored FRAGMENT-MAJOR: the exact 16x16x32-bf16 MFMA operand
// register layout (lane = (m|n)&15 | octet<<4, 8 contiguous shorts per lane),
// so GEMM kernels load operands straight into VGPRs -> no LDS, no K-loop
// barriers.
// qkv GEMM is 2-TERM bf16x2 (A_hi*W_hi + A_lo*W_hi). Dropped-term error
// sigma ~= 1.1e-3; band 0.008 = 7.1 sigma. Borderline outputs -> rescue.
// Rescue append is LDS-staged per block + ONE global atomicAdd per p-pass
// (R2 lesson: 40K same-address device atomics serialize ~350us at one L2 bank).
// R4: p-loop INSIDE the block: 512 blocks = exactly 2/CU, ONE scheduling
// round; A-slice re-read per p hits L1/L2 hot (R3 lesson: wall was
// insensitive to per-iter work -> per-block-round latency chain).
#define OFF_A2     0ull            // [mb][gi 0..7][ktA 0..15][lane][8] = 64 MB
#define OFF_BQ     67108864ull     // [gj 0..47][ktB 0..7][lane][8] = 393,216 (hi only)
#define OFF_BP     67502080ull     // [gj 0..15][ktB 0..23][lane][8] = 393,216 (3-term)
#define OFF_QM     67895296ull     // qmask u32 [g][s][h] = 2,097,152
#define OFF_KB     69992448ull     // 2,097,152
#define OFF_VB     72089600ull     // 2,097,152
#define OFF_KV     74186752ull     // 16,777,216
#define OFF_KCS    90963968ull     // 524,288
#define OFF_PART   91488256ull     // 524,288
#define OFF_REGION 92012544ull     // 131,072
#define OFF_IDX    92143616ull     // 2,048
#define OFF_RL     92145664ull     // 524,288 (131072 entries)
#define OFF_RC     92669952ull     // 16

typedef short short8 __attribute__((ext_vector_type(8)));
typedef float floatx4 __attribute__((ext_vector_type(4)));

__device__ __forceinline__ short f2bf(float f) {
    unsigned u = __float_as_uint(f);
    unsigned r = (u + 0x7fffu + ((u >> 16) & 1u)) >> 16;
    return (short)r;
}
__device__ __forceinline__ float bf2f(short h) {
    return __uint_as_float(((unsigned)(unsigned short)h) << 16);
}

// g = (t*B_+b)*NW_ + n, s in [0,128): float index of x[t,b,lt,lh,lw,0]
__device__ __forceinline__ int xoff_row(int g, int s) {
    int tb = g >> 6;
    int n  = g & 63;
    int iwt = n >> 4, iwh = (n >> 2) & 3, iww = n & 3;
    int ipt = s >> 6, iph = (s >> 3) & 7, ipw = s & 7;
    int lt = iwt * 2 + ipt, lh = iwh * 8 + iph, lw = iww * 8 + ipw;
    return (((tb * 8 + lt) * 32 + lh) * 32 + lw) * 256;
}

// ---- K1a: partial sums + write A2 in fragment-major bf16 hi/lo ----
__global__ __launch_bounds__(256) void k_partial_split(const float* __restrict__ x,
        float* __restrict__ part, short* __restrict__ A2) {
    int g = blockIdx.x;            // 512
    int c = threadIdx.x;
    const int ktAh = c >> 5, ktAl = 8 + (c >> 5);
    const int octsh = ((c >> 3) & 3) << 4, sub = c & 7;
    float acc = 0.f;
    for (int s = 0; s < WS_; ++s) {
        float v = x[xoff_row(g, s) + c];
        acc += v;
        short hi = f2bf(v);
        short lo = f2bf(v - bf2f(hi));
        int lane = (s & 15) | octsh;
        size_t base = ((size_t)(g * 8 + (s >> 4))) * 16;
        A2[(base + ktAh) * 512 + lane * 8 + sub] = hi;
        A2[(base + ktAl) * 512 + lane * 8 + sub] = lo;
    }
    part[g * C_ + c] = acc;
}

// ---- K1b: region[b,n,c] = sum_t part / 128 ----
__global__ __launch_bounds__(256) void k_region(const float* __restrict__ part,
                                                float* __restrict__ region) {
    int bn = blockIdx.x;           // 128
    int c = threadIdx.x;
    int b = bn >> 6, n = bn & 63;
    float acc = 0.f;
    for (int t = 0; t < T_; ++t) acc += part[((t * 2 + b) * 64 + n) * C_ + c];
    region[bn * C_ + c] = acc * (1.0f / 128.0f);
}

// ---- K2: scores + top-4 (lowest-index tie-break) ----
__global__ __launch_bounds__(64) void k_scores(const float* __restrict__ region,
                                               int* __restrict__ idx) {
    int bi = blockIdx.x;           // 128
    int b = bi >> 6, i = bi & 63;
    int tid = threadIdx.x;
    __shared__ float ri[C_];
    __shared__ float sc[64];
    for (int c = tid; c < C_; c += 64) ri[c] = region[(b * 64 + i) * C_ + c];
    __syncthreads();
    const float* rj = region + (size_t)(b * 64 + tid) * C_;
    float dot = 0.f;
    for (int c = 0; c < C_; ++c) dot += ri[c] * rj[c];
    sc[tid] = dot * 0.17677669529663687f;
    __syncthreads();
    if (tid == 0) {
        for (int kk = 0; kk < TOPK_; ++kk) {
            float best = -INFINITY; int bj = 0;
            for (int j = 0; j < 64; ++j)
                if (sc[j] > best) { best = sc[j]; bj = j; }
            idx[bi * TOPK_ + kk] = bj;
            sc[bj] = -INFINITY;
        }
    }
}

// ---- B' builders, fragment-major ----
// Bq: hi(W) only, 8 k-tiles (2-term scheme shares B between A_hi and A_lo).
__global__ __launch_bounds__(256) void b_build_qkv(const float* __restrict__ W,
                                                   short* __restrict__ Bq) {
    int ke = blockIdx.x;                     // 0..255 (hi only)
    int n = blockIdx.y * 256 + threadIdx.x;  // 0..767
    float wv = W[(size_t)ke * NC3 + n];
    short o = f2bf(wv);
    int gj = n >> 4, lmn = n & 15, ktB = ke >> 5, oct = (ke >> 3) & 3, sub = ke & 7;
    Bq[(size_t)((gj * 8 + ktB) * 64 + (lmn | (oct << 4))) * 8 + sub] = o;
}
// Bp: 3-term [hi | hi | lo], 24 k-tiles (proj must stay exact to tolerance).
__global__ __launch_bounds__(256) void b_build_proj(const float* __restrict__ W,
                                                    short* __restrict__ Bp) {
    int ke = blockIdx.x;                // 0..767
    int n = threadIdx.x;                // 0..255
    float wv = W[(size_t)(ke & 255) * 256 + n];
    short hi = f2bf(wv);
    short o = (ke < 512) ? hi : f2bf(wv - bf2f(hi));
    int gj = n >> 4, lmn = n & 15, ktB = ke >> 5, oct = (ke >> 3) & 3, sub = ke & 7;
    Bp[(size_t)((gj * 24 + ktB) * 64 + (lmn | (oct << 4))) * 8 + sub] = o;
}

__device__ __forceinline__ unsigned p4(unsigned xv) {
    return (xv & 1u) | ((xv >> 7) & 2u) | ((xv >> 14) & 4u) | ((xv >> 21) & 8u);
}

// ---- K3: qkv GEMM, fragment-direct (NO LDS in K-loop, NO barriers).
// grid 512 = one block per mb = exactly 2 blocks/CU, single scheduling round.
// p-loop inside: 3 K-loops over the SAME A-slice (L1/L2-hot re-reads).
__global__ __launch_bounds__(256, 2) void qkv_mfma(const short* __restrict__ A2,
        const short* __restrict__ Bq, const float* __restrict__ bias,
        unsigned* __restrict__ qm, unsigned* __restrict__ kb,
        unsigned* __restrict__ vb, unsigned* __restrict__ rl,
        unsigned* __restrict__ rcnt) {
    __shared__ unsigned char sp[128 * 264];
    __shared__ unsigned rbuf[RBCAP];
    __shared__ unsigned lcnt, sbase;
    const int mb = blockIdx.x;             // 0..511
    const int tid = threadIdx.x;
    const int wv = tid >> 6, lane = tid & 63;
    const int wm = wv >> 1, wn = wv & 1;
    const int lm = lane & 15, lq = lane >> 4;

    const short* Ab = A2 + ((size_t)(mb * 8 + wm * 4) * 16) * 512 + lane * 8;

    for (int p = 0; p < 3; ++p) {
        if (tid == 0) lcnt = 0;
        __syncthreads();                   // also fences sp reuse from prev p

        floatx4 acc[4][8];
#pragma unroll
        for (int i = 0; i < 4; ++i)
#pragma unroll
            for (int j = 0; j < 8; ++j) acc[i][j] = (floatx4)0.f;

        const short* Bb = Bq + ((size_t)(p * 16 + wn * 8) * 8) * 512 + lane * 8;

        for (int ktB = 0; ktB < 8; ++ktB) {
            short8 bf[8];
#pragma unroll
            for (int j = 0; j < 8; ++j)
                bf[j] = *(const short8*)(Bb + (size_t)(j * 8 + ktB) * 512);
            short8 ah[4];
#pragma unroll
            for (int i = 0; i < 4; ++i)
                ah[i] = *(const short8*)(Ab + (size_t)(i * 16 + ktB) * 512);
#pragma unroll
            for (int i = 0; i < 4; ++i)
#pragma unroll
                for (int j = 0; j < 8; ++j)
                    acc[i][j] = __builtin_amdgcn_mfma_f32_16x16x32_bf16(
                        ah[i], bf[j], acc[i][j], 0, 0, 0);
            short8 al[4];
#pragma unroll
            for (int i = 0; i < 4; ++i)
                al[i] = *(const short8*)(Ab + (size_t)(i * 16 + 8 + ktB) * 512);
#pragma unroll
            for (int i = 0; i < 4; ++i)
#pragma unroll
                for (int j = 0; j < 8; ++j)
                    acc[i][j] = __builtin_amdgcn_mfma_f32_16x16x32_bf16(
                        al[i], bf[j], acc[i][j], 0, 0, 0);
        }

        // epilogue: spikes into LDS; borderline -> LDS rescue staging
#pragma unroll
        for (int i = 0; i < 4; ++i) {
#pragma unroll
            for (int j = 0; j < 8; ++j) {
                int cb = wn * 128 + j * 16 + lm;
                int cg = p * 256 + cb;
                float bj = bias[cg];
#pragma unroll
                for (int r = 0; r < 4; ++r) {
                    int s = wm * 64 + i * 16 + lq * 4 + r;
                    float v = acc[i][j][r] + bj;
                    if (fabsf(v - 2.0f) < BAND) {
                        unsigned ent = ((unsigned)mb << 17) | ((unsigned)s << 10) | (unsigned)cg;
                        unsigned slot = atomicAdd(&lcnt, 1u);
                        if (slot < RBCAP) {
                            rbuf[slot] = ent;
                        } else {                       // overflow fallback (cold)
                            unsigned gs = atomicAdd(rcnt, 1u);
                            if (gs < RCAP) rl[gs] = ent;
                        }
                    }
                    sp[s * 264 + cb] = (v >= 2.0f) ? 1 : 0;
                }
            }
        }
        __syncthreads();

        // bulk-reserve rescue slots: ONE global atomic per block per p
        unsigned cnt = lcnt;
        if (cnt > RBCAP) cnt = RBCAP;
        if (tid == 0) sbase = atomicAdd(rcnt, cnt);
        __syncthreads();
        for (unsigned e = tid; e < cnt; e += 256) {
            unsigned slot = sbase + e;
            if (slot < RCAP) rl[slot] = rbuf[e];
        }

        if (p == 0) {
            // pack q bitmasks over channel-within-head: qm[g][s][h]
            const unsigned* spw = (const unsigned*)sp;   // pitch 66 words
#pragma unroll
            for (int t = 0; t < 4; ++t) {
                int w = t * 256 + tid;
                int s = w >> 3, h = w & 7;
                unsigned m = 0;
#pragma unroll
                for (int q = 0; q < 8; ++q)
                    m |= p4(spw[s * 66 + h * 8 + q]) << (q * 4);
                qm[(size_t)mb * 1024 + w] = m;
            }
        } else {
            // pack k/v bitmasks along s: (kb|vb)[(mb*256+c)*4 + w2]
            unsigned wrd[4];
#pragma unroll
            for (int w2 = 0; w2 < 4; ++w2) {
                unsigned m = 0;
#pragma unroll
                for (int ii = 0; ii < 32; ++ii)
                    m |= (unsigned)(sp[(w2 * 32 + ii) * 264 + tid] & 1) << ii;
                wrd[w2] = m;
            }
            uint4 o; o.x = wrd[0]; o.y = wrd[1]; o.z = wrd[2]; o.w = wrd[3];
            *(uint4*)(((p == 1) ? kb : vb) + ((size_t)mb * 256 + tid) * 4) = o;
        }
        // loop-top __syncthreads() fences sp/rbuf reuse for next p
    }
}

// ---- rescue: LANE-PARALLEL serial ascending-k fp32 FMA per entry.
// Per-entry summation order identical to the validated serial rescue.
__global__ __launch_bounds__(256) void rescue_fix(const float* __restrict__ x,
        const float* __restrict__ W, const float* __restrict__ bias,
        const unsigned* __restrict__ rl, const unsigned* __restrict__ rcnt,
        unsigned* __restrict__ qm, unsigned* __restrict__ kb,
        unsigned* __restrict__ vb) {
    unsigned n = *rcnt; if (n > RCAP) n = RCAP;
    unsigned gid = blockIdx.x * 256 + threadIdx.x;
    unsigned stride = gridDim.x * 256;
    for (unsigned e = gid; e < n; e += stride) {
        unsigned ent = rl[e];
        int mb = ent >> 17, s = (ent >> 10) & 127, cg = ent & 1023;
        const float* ar = x + xoff_row(mb, s);
        const float* wc = W + cg;
        float da = 0.f;
#pragma unroll 4
        for (int k4 = 0; k4 < 64; ++k4) {
            float4 a4 = *(const float4*)(ar + k4 * 4);
            da = fmaf(a4.x, wc[(size_t)(k4 * 4 + 0) * NC3], da);
            da = fmaf(a4.y, wc[(size_t)(k4 * 4 + 1) * NC3], da);
            da = fmaf(a4.z, wc[(size_t)(k4 * 4 + 2) * NC3], da);
            da = fmaf(a4.w, wc[(size_t)(k4 * 4 + 3) * NC3], da);
        }
        da += bias[cg];
        int spk = (da >= 2.0f) ? 1 : 0;
        if (cg < 256) {
            int h = cg >> 5, d = cg & 31;
            unsigned* wp = qm + (size_t)mb * 1024 + s * 8 + h;
            unsigned bit = 1u << d;
            int have = (*wp & bit) ? 1 : 0;
            if (have != spk) atomicXor(wp, bit);
        } else {
            unsigned* tgt = (cg < 512) ? kb : vb;
            int c = cg & 255;
            unsigned* wp = tgt + ((size_t)mb * 256 + c) * 4 + (s >> 5);
            unsigned bit = 1u << (s & 31);
            int have = (*wp & bit) ? 1 : 0;
            if (have != spk) atomicXor(wp, bit);
        }
    }
}

// ---- K3.5: column sums of k spikes from bitmasks ----
__global__ __launch_bounds__(256) void kcs_bits(const unsigned* __restrict__ kb,
                                                float* __restrict__ kcs) {
    int g = blockIdx.x;
    int c = threadIdx.x;
    const unsigned* p = kb + ((size_t)g * 256 + c) * 4;
    int acc = __popc(p[0]) + __popc(p[1]) + __popc(p[2]) + __popc(p[3]);
    kcs[g * C_ + c] = (float)acc;
}

// ---- K4: kv[g,h,d,e] = popcount over gathered s-bitmasks (exact int) ----
__global__ __launch_bounds__(256) void kv_bits(const unsigned* __restrict__ kb,
        const unsigned* __restrict__ vb, const int* __restrict__ idx,
        float* __restrict__ kvbuf) {
    int g = blockIdx.x;            // 512
    int tb = g >> 6, n = g & 63, b = tb & 1;
    int tid = threadIdx.x;
    __shared__ uint4 kbl[1024];
    __shared__ uint4 vbl[1024];
    __shared__ int widx[TOPK_];
    if (tid < TOPK_) widx[tid] = idx[(b * 64 + n) * TOPK_ + tid];
    __syncthreads();
#pragma unroll
    for (int kk = 0; kk < TOPK_; ++kk) {
        int g2 = tb * 64 + widx[kk];
        kbl[kk * 256 + tid] = *(const uint4*)&kb[((size_t)g2 * 256 + tid) * 4];
        vbl[kk * 256 + tid] = *(const uint4*)&vb[((size_t)g2 * 256 + tid) * 4];
    }
    __syncthreads();
    int h = tid >> 5, e = tid & 31;
    uint4 vw0 = vbl[0 * 256 + h * 32 + e];
    uint4 vw1 = vbl[1 * 256 + h * 32 + e];
    uint4 vw2 = vbl[2 * 256 + h * 32 + e];
    uint4 vw3 = vbl[3 * 256 + h * 32 + e];
    for (int d = 0; d < 32; ++d) {
        uint4 k0 = kbl[0 * 256 + h * 32 + d];
        uint4 k1 = kbl[1 * 256 + h * 32 + d];
        uint4 k2 = kbl[2 * 256 + h * 32 + d];
        uint4 k3 = kbl[3 * 256 + h * 32 + d];
        int acc = __popc(k0.x & vw0.x) + __popc(k0.y & vw0.y)
                + __popc(k0.z & vw0.z) + __popc(k0.w & vw0.w)
                + __popc(k1.x & vw1.x) + __popc(k1.y & vw1.y)
                + __popc(k1.z & vw1.z) + __popc(k1.w & vw1.w)
                + __popc(k2.x & vw2.x) + __popc(k2.y & vw2.y)
                + __popc(k2.z & vw2.z) + __popc(k2.w & vw2.w)
                + __popc(k3.x & vw3.x) + __popc(k3.y & vw3.y)
                + __popc(k3.z & vw3.z) + __popc(k3.w & vw3.w);
        kvbuf[((size_t)(g * 8 + h) * 32 + d) * 32 + e] = (float)acc;
    }
}

// ---- K5: FUSED attn + proj. One block = 32 rows of one window g. ----
__global__ __launch_bounds__(256) void attn_proj(const unsigned* __restrict__ qm,
        const float* __restrict__ kvbuf, const float* __restrict__ kcs,
        const int* __restrict__ idx, const short* __restrict__ Bp,
        const float* __restrict__ bias, float* __restrict__ out) {
    __shared__ __align__(16) short aw[16384];   // 32 KB frags; reused as float ow[32][256]
    __shared__ unsigned qb[256];
    __shared__ float ksl[256];
    __shared__ int widx[TOPK_];
    const int bid = blockIdx.x;        // 2048
    const int g = bid >> 2, qr = bid & 3;
    const int tb = g >> 6, n = g & 63, b = tb & 1;
    const int tid = threadIdx.x;
    if (tid < TOPK_) widx[tid] = idx[(b * 64 + n) * TOPK_ + tid];
    __syncthreads();
    float ks = 0.f;
#pragma unroll
    for (int kk = 0; kk < TOPK_; ++kk)
        ks += kcs[(size_t)(tb * 64 + widx[kk]) * C_ + tid];
    ksl[tid] = ks;
    qb[tid] = qm[(size_t)g * 1024 + qr * 256 + tid];
    __syncthreads();

    const int h = tid >> 5, e = tid & 31;
    float kvr[32], ksr[32];
#pragma unroll
    for (int d = 0; d < 32; ++d)
        kvr[d] = kvbuf[((size_t)(g * 8 + h) * 32 + d) * 32 + e];
#pragma unroll
    for (int d = 0; d < 32; ++d) ksr[d] = ksl[h * 32 + d];

    const int ktAh = tid >> 5, ktAl = 8 + (tid >> 5);
    const int octsh = ((tid >> 3) & 3) << 4, sub = tid & 7;
    for (int sl = 0; sl < 32; ++sl) {
        unsigned qw = qb[sl * 8 + h];
        float r;
        if (qw == 0u) {
            r = 0.f;
        } else {
            float num = 0.f, den = 0.f;
#pragma unroll
            for (int d = 0; d < 32; ++d) {
                float m = (float)((qw >> d) & 1u);
                num = fmaf(m, kvr[d], num);
                den = fmaf(m, ksr[d], den);
            }
            r = num / (den + 1e-6f);
        }
        short hi = f2bf(r), lo = f2bf(r - bf2f(hi));
        int lane2 = (sl & 15) | octsh;
        int gi = sl >> 4;
        aw[((gi * 16 + ktAh) * 64 + lane2) * 8 + sub] = hi;
        aw[((gi * 16 + ktAl) * 64 + lane2) * 8 + sub] = lo;
    }
    __syncthreads();

    // proj: M=32, N=256; 4 waves each N=64
    const int wvw = tid >> 6, lane = tid & 63;
    const int lm = lane & 15, lq = lane >> 4;
    floatx4 pacc[2][4];
#pragma unroll
    for (int i = 0; i < 2; ++i)
#pragma unroll
        for (int j = 0; j < 4; ++j) pacc[i][j] = (floatx4)0.f;
    const short* Bb = Bp + ((size_t)(wvw * 4) * 24) * 512 + lane * 8;
#pragma unroll 2
    for (int kt = 0; kt < 24; ++kt) {
        int ktA = (kt < 16) ? kt : kt - 16;
        short8 af[2], bf[4];
#pragma unroll
        for (int i = 0; i < 2; ++i)
            af[i] = *(const short8*)&aw[((i * 16 + ktA) * 64 + lane) * 8];
#pragma unroll
        for (int j = 0; j < 4; ++j)
            bf[j] = *(const short8*)(Bb + (size_t)(j * 24 + kt) * 512);
#pragma unroll
        for (int i = 0; i < 2; ++i)
#pragma unroll
            for (int j = 0; j < 4; ++j)
                pacc[i][j] = __builtin_amdgcn_mfma_f32_16x16x32_bf16(
                    af[i], bf[j], pacc[i][j], 0, 0, 0);
    }
    __syncthreads();

    float* ow = (float*)aw;            // 32 x 256 fp32 rows
#pragma unroll
    for (int i = 0; i < 2; ++i) {
#pragma unroll
        for (int j = 0; j < 4; ++j) {
            int c = wvw * 64 + j * 16 + lm;
            float bj = bias[c];
#pragma unroll
            for (int r = 0; r < 4; ++r)
                ow[(i * 16 + lq * 4 + r) * 256 + c] = pacc[i][j][r] + bj;
        }
    }
    __syncthreads();

    // coalesced un-windowize store: rows are contiguous 1 KB in out
    int sl2 = tid >> 3, pc = (tid & 7) * 32;
    int off = xoff_row(g, qr * 32 + sl2) + pc;
#pragma unroll
    for (int q = 0; q < 8; ++q)
        *(float4*)(out + off + q * 4) = *(const float4*)&ow[sl2 * 256 + pc + q * 4];
}

extern "C" void kernel_launch(void* const* d_in, const int* in_sizes, int n_in,
                              void* d_out, int out_size, void* d_ws, size_t ws_size,
                              hipStream_t stream) {
    (void)in_sizes; (void)n_in; (void)out_size; (void)ws_size;
    const float* x    = (const float*)d_in[0];
    const float* Wqkv = (const float*)d_in[1];
    const float* bqkv = (const float*)d_in[2];
    const float* Wp   = (const float*)d_in[3];
    const float* bp   = (const float*)d_in[4];
    char* ws = (char*)d_ws;
    short*    A2    = (short*)   (ws + OFF_A2);
    short*    Bq    = (short*)   (ws + OFF_BQ);
    short*    Bpj   = (short*)   (ws + OFF_BP);
    unsigned* qmv   = (unsigned*)(ws + OFF_QM);
    unsigned* kb    = (unsigned*)(ws + OFF_KB);
    unsigned* vb    = (unsigned*)(ws + OFF_VB);
    float*    kvbuf = (float*)   (ws + OFF_KV);
    float*    kcs   = (float*)   (ws + OFF_KCS);
    float*    part  = (float*)   (ws + OFF_PART);
    float*    region= (float*)   (ws + OFF_REGION);
    int*      idxb  = (int*)     (ws + OFF_IDX);
    unsigned* rl    = (unsigned*)(ws + OFF_RL);
    unsigned* rcnt  = (unsigned*)(ws + OFF_RC);
    float*    out   = (float*)d_out;

    hipMemsetAsync(rcnt, 0, 4, stream);
    b_build_qkv    <<<dim3(256, 3), 256, 0, stream>>>(Wqkv, Bq);
    b_build_proj   <<<768, 256, 0, stream>>>(Wp, Bpj);
    k_partial_split<<<512, 256, 0, stream>>>(x, part, A2);
    k_region       <<<128, 256, 0, stream>>>(part, region);
    k_scores       <<<128,  64, 0, stream>>>(region, idxb);
    qkv_mfma       <<<512, 256, 0, stream>>>(A2, Bq, bqkv, qmv, kb, vb, rl, rcnt);
    rescue_fix     <<<256, 256, 0, stream>>>(x, Wqkv, bqkv, rl, rcnt, qmv, kb, vb);
    kcs_bits       <<<512, 256, 0, stream>>>(kb, kcs);
    kv_bits        <<<512, 256, 0, stream>>>(kb, vb, idxb, kvbuf);
    attn_proj      <<<2048, 256, 0, stream>>>(qmv, kvbuf, kcs, idxb, Bpj, bp, out);
}

// Round 5
// 272.105 us; speedup vs baseline: 1.3029x; 1.3029x over previous
//
#include <hip/hip_runtime.h>
#include <cstdint>
#include <cstddef>

// Problem constants (fixed by reference shapes)
#define T_    4
#define B_    2
#define NW_   64
#define WS_   128
#define C_    256
#define NC3   768
#define H_    8
#define HD_   32
#define TOPK_ 4
#define RCAP  131072
#define BAND  0.008f
#define RBCAP 512          // per-block LDS rescue staging capacity

// Workspace layout (bytes, all 16B aligned). Total ~92.7 MB.
// A2/Bq/Bp are stored FRAGMENT-MAJOR: the exact 16x16x32-bf16 MFMA operand
// register layout (lane = (m|n)&15 | octet<<4, 8 contiguous shorts per lane),
// so GEMM kernels load operands straight into VGPRs -> no LDS, no K-loop
// barriers.
// qkv GEMM is 2-TERM bf16x2 (A_hi*W_hi + A_lo*W_hi). Dropped-term error
// sigma ~= 1.1e-3; band 0.008 = 7.1 sigma. Borderline outputs -> rescue.
// Rescue append is LDS-staged per block + ONE global atomicAdd per block
// (R2 lesson: 40K same-address device atomics serialize ~350us at one L2 bank).
// R4 lesson: folding the p-loop inside the block made the compiler unroll
// trip-3 and spill acc to scratch (137 MB scratch writes, MfmaUtil 0.1%).
// qkv stays at the validated R3 structure: grid 1536, p from blockIdx.
#define OFF_A2     0ull            // [mb][gi 0..7][ktA 0..15][lane][8] = 64 MB
#define OFF_BQ     67108864ull     // [gj 0..47][ktB 0..7][lane][8] = 393,216 (hi only)
#define OFF_BP     67502080ull     // [gj 0..15][ktB 0..23][lane][8] = 393,216 (3-term)
#define OFF_QM     67895296ull     // qmask u32 [g][s][h] = 2,097,152
#define OFF_KB     69992448ull     // 2,097,152
#define OFF_VB     72089600ull     // 2,097,152
#define OFF_KV     74186752ull     // 16,777,216
#define OFF_KCS    90963968ull     // 524,288
#define OFF_PART   91488256ull     // 524,288
#define OFF_REGION 92012544ull     // 131,072
#define OFF_IDX    92143616ull     // 2,048
#define OFF_RL     92145664ull     // 524,288 (131072 entries)
#define OFF_RC     92669952ull     // 16

typedef short short8 __attribute__((ext_vector_type(8)));
typedef float floatx4 __attribute__((ext_vector_type(4)));

__device__ __forceinline__ short f2bf(float f) {
    unsigned u = __float_as_uint(f);
    unsigned r = (u + 0x7fffu + ((u >> 16) & 1u)) >> 16;
    return (short)r;
}
__device__ __forceinline__ float bf2f(short h) {
    return __uint_as_float(((unsigned)(unsigned short)h) << 16);
}

// g = (t*B_+b)*NW_ + n, s in [0,128): float index of x[t,b,lt,lh,lw,0]
__device__ __forceinline__ int xoff_row(int g, int s) {
    int tb = g >> 6;
    int n  = g & 63;
    int iwt = n >> 4, iwh = (n >> 2) & 3, iww = n & 3;
    int ipt = s >> 6, iph = (s >> 3) & 7, ipw = s & 7;
    int lt = iwt * 2 + ipt, lh = iwh * 8 + iph, lw = iww * 8 + ipw;
    return (((tb * 8 + lt) * 32 + lh) * 32 + lw) * 256;
}

// ---- K1a: partial sums + write A2 in fragment-major bf16 hi/lo ----
__global__ __launch_bounds__(256) void k_partial_split(const float* __restrict__ x,
        float* __restrict__ part, short* __restrict__ A2) {
    int g = blockIdx.x;            // 512
    int c = threadIdx.x;
    const int ktAh = c >> 5, ktAl = 8 + (c >> 5);
    const int octsh = ((c >> 3) & 3) << 4, sub = c & 7;
    float acc = 0.f;
    for (int s = 0; s < WS_; ++s) {
        float v = x[xoff_row(g, s) + c];
        acc += v;
        short hi = f2bf(v);
        short lo = f2bf(v - bf2f(hi));
        int lane = (s & 15) | octsh;
        size_t base = ((size_t)(g * 8 + (s >> 4))) * 16;
        A2[(base + ktAh) * 512 + lane * 8 + sub] = hi;
        A2[(base + ktAl) * 512 + lane * 8 + sub] = lo;
    }
    part[g * C_ + c] = acc;
}

// ---- K1b: region[b,n,c] = sum_t part / 128 ----
__global__ __launch_bounds__(256) void k_region(const float* __restrict__ part,
                                                float* __restrict__ region) {
    int bn = blockIdx.x;           // 128
    int c = threadIdx.x;
    int b = bn >> 6, n = bn & 63;
    float acc = 0.f;
    for (int t = 0; t < T_; ++t) acc += part[((t * 2 + b) * 64 + n) * C_ + c];
    region[bn * C_ + c] = acc * (1.0f / 128.0f);
}

// ---- K2: scores + top-4 (lowest-index tie-break) ----
__global__ __launch_bounds__(64) void k_scores(const float* __restrict__ region,
                                               int* __restrict__ idx) {
    int bi = blockIdx.x;           // 128
    int b = bi >> 6, i = bi & 63;
    int tid = threadIdx.x;
    __shared__ float ri[C_];
    __shared__ float sc[64];
    for (int c = tid; c < C_; c += 64) ri[c] = region[(b * 64 + i) * C_ + c];
    __syncthreads();
    const float* rj = region + (size_t)(b * 64 + tid) * C_;
    float dot = 0.f;
    for (int c = 0; c < C_; ++c) dot += ri[c] * rj[c];
    sc[tid] = dot * 0.17677669529663687f;
    __syncthreads();
    if (tid == 0) {
        for (int kk = 0; kk < TOPK_; ++kk) {
            float best = -INFINITY; int bj = 0;
            for (int j = 0; j < 64; ++j)
                if (sc[j] > best) { best = sc[j]; bj = j; }
            idx[bi * TOPK_ + kk] = bj;
            sc[bj] = -INFINITY;
        }
    }
}

// ---- B' builders, fragment-major ----
// Bq: hi(W) only, 8 k-tiles (2-term scheme shares B between A_hi and A_lo).
__global__ __launch_bounds__(256) void b_build_qkv(const float* __restrict__ W,
                                                   short* __restrict__ Bq) {
    int ke = blockIdx.x;                     // 0..255 (hi only)
    int n = blockIdx.y * 256 + threadIdx.x;  // 0..767
    float wv = W[(size_t)ke * NC3 + n];
    short o = f2bf(wv);
    int gj = n >> 4, lmn = n & 15, ktB = ke >> 5, oct = (ke >> 3) & 3, sub = ke & 7;
    Bq[(size_t)((gj * 8 + ktB) * 64 + (lmn | (oct << 4))) * 8 + sub] = o;
}
// Bp: 3-term [hi | hi | lo], 24 k-tiles (proj must stay exact to tolerance).
__global__ __launch_bounds__(256) void b_build_proj(const float* __restrict__ W,
                                                    short* __restrict__ Bp) {
    int ke = blockIdx.x;                // 0..767
    int n = threadIdx.x;                // 0..255
    float wv = W[(size_t)(ke & 255) * 256 + n];
    short hi = f2bf(wv);
    short o = (ke < 512) ? hi : f2bf(wv - bf2f(hi));
    int gj = n >> 4, lmn = n & 15, ktB = ke >> 5, oct = (ke >> 3) & 3, sub = ke & 7;
    Bp[(size_t)((gj * 24 + ktB) * 64 + (lmn | (oct << 4))) * 8 + sub] = o;
}

__device__ __forceinline__ unsigned p4(unsigned xv) {
    return (xv & 1u) | ((xv >> 7) & 2u) | ((xv >> 14) & 4u) | ((xv >> 21) & 8u);
}

// ---- K3: qkv GEMM, fragment-direct (NO LDS in K-loop, NO barriers).
// 2-term: per ktB, load B-hi frags ONCE, use with both A-hi and A-lo.
// Rescue: LDS-staged, one global atomicAdd per block (bulk reservation).
// (Exact R3 kernel: 103 us measured.)
__global__ __launch_bounds__(256, 2) void qkv_mfma(const short* __restrict__ A2,
        const short* __restrict__ Bq, const float* __restrict__ bias,
        unsigned* __restrict__ qm, unsigned* __restrict__ kb,
        unsigned* __restrict__ vb, unsigned* __restrict__ rl,
        unsigned* __restrict__ rcnt) {
    __shared__ unsigned char sp[128 * 264];
    __shared__ unsigned rbuf[RBCAP];
    __shared__ unsigned lcnt, sbase;
    const int bid = blockIdx.x;            // 0..1535
    const int x8 = bid & 7;
    const int y = bid >> 3;                // 0..191
    const int p = y % 3;
    const int mb = x8 + ((y / 3) << 3);    // bijective: all (mb,p) covered
    const int tid = threadIdx.x;
    const int wv = tid >> 6, lane = tid & 63;
    const int wm = wv >> 1, wn = wv & 1;
    const int lm = lane & 15, lq = lane >> 4;

    if (tid == 0) lcnt = 0;
    __syncthreads();

    floatx4 acc[4][8];
#pragma unroll
    for (int i = 0; i < 4; ++i)
#pragma unroll
        for (int j = 0; j < 8; ++j) acc[i][j] = (floatx4)0.f;

    const short* Ab = A2 + ((size_t)(mb * 8 + wm * 4) * 16) * 512 + lane * 8;
    const short* Bb = Bq + ((size_t)(p * 16 + wn * 8) * 8) * 512 + lane * 8;

    for (int ktB = 0; ktB < 8; ++ktB) {
        short8 ah[4], al[4], bf[8];
#pragma unroll
        for (int j = 0; j < 8; ++j)
            bf[j] = *(const short8*)(Bb + (size_t)(j * 8 + ktB) * 512);
#pragma unroll
        for (int i = 0; i < 4; ++i) {
            ah[i] = *(const short8*)(Ab + (size_t)(i * 16 + ktB) * 512);
            al[i] = *(const short8*)(Ab + (size_t)(i * 16 + 8 + ktB) * 512);
        }
#pragma unroll
        for (int i = 0; i < 4; ++i)
#pragma unroll
            for (int j = 0; j < 8; ++j)
                acc[i][j] = __builtin_amdgcn_mfma_f32_16x16x32_bf16(
                    ah[i], bf[j], acc[i][j], 0, 0, 0);
#pragma unroll
        for (int i = 0; i < 4; ++i)
#pragma unroll
            for (int j = 0; j < 8; ++j)
                acc[i][j] = __builtin_amdgcn_mfma_f32_16x16x32_bf16(
                    al[i], bf[j], acc[i][j], 0, 0, 0);
    }

    // epilogue: spikes into LDS; borderline -> LDS rescue staging
#pragma unroll
    for (int i = 0; i < 4; ++i) {
#pragma unroll
        for (int j = 0; j < 8; ++j) {
            int cb = wn * 128 + j * 16 + lm;
            int cg = p * 256 + cb;
            float bj = bias[cg];
#pragma unroll
            for (int r = 0; r < 4; ++r) {
                int s = wm * 64 + i * 16 + lq * 4 + r;
                float v = acc[i][j][r] + bj;
                if (fabsf(v - 2.0f) < BAND) {
                    unsigned ent = ((unsigned)mb << 17) | ((unsigned)s << 10) | (unsigned)cg;
                    unsigned slot = atomicAdd(&lcnt, 1u);
                    if (slot < RBCAP) {
                        rbuf[slot] = ent;
                    } else {                       // overflow fallback (cold)
                        unsigned gs = atomicAdd(rcnt, 1u);
                        if (gs < RCAP) rl[gs] = ent;
                    }
                }
                sp[s * 264 + cb] = (v >= 2.0f) ? 1 : 0;
            }
        }
    }
    __syncthreads();

    // bulk-reserve rescue slots: ONE global atomic per block
    unsigned cnt = lcnt;
    if (cnt > RBCAP) cnt = RBCAP;
    if (tid == 0) sbase = atomicAdd(rcnt, cnt);
    __syncthreads();
    for (unsigned e = tid; e < cnt; e += 256) {
        unsigned slot = sbase + e;
        if (slot < RCAP) rl[slot] = rbuf[e];
    }

    if (p == 0) {
        // pack q bitmasks over channel-within-head: qm[g][s][h]
        const unsigned* spw = (const unsigned*)sp;   // pitch 66 words
#pragma unroll
        for (int t = 0; t < 4; ++t) {
            int w = t * 256 + tid;
            int s = w >> 3, h = w & 7;
            unsigned m = 0;
#pragma unroll
            for (int q = 0; q < 8; ++q)
                m |= p4(spw[s * 66 + h * 8 + q]) << (q * 4);
            qm[(size_t)mb * 1024 + w] = m;
        }
    } else {
        // pack k/v bitmasks along s: (kb|vb)[(mb*256+c)*4 + w2]
        unsigned wrd[4];
#pragma unroll
        for (int w2 = 0; w2 < 4; ++w2) {
            unsigned m = 0;
#pragma unroll
            for (int ii = 0; ii < 32; ++ii)
                m |= (unsigned)(sp[(w2 * 32 + ii) * 264 + tid] & 1) << ii;
            wrd[w2] = m;
        }
        uint4 o; o.x = wrd[0]; o.y = wrd[1]; o.z = wrd[2]; o.w = wrd[3];
        *(uint4*)(((p == 1) ? kb : vb) + ((size_t)mb * 256 + tid) * 4) = o;
    }
}

// ---- rescue: LANE-PARALLEL serial ascending-k fp32 FMA per entry.
// Per-entry summation order identical to the validated serial rescue.
__global__ __launch_bounds__(256) void rescue_fix(const float* __restrict__ x,
        const float* __restrict__ W, const float* __restrict__ bias,
        const unsigned* __restrict__ rl, const unsigned* __restrict__ rcnt,
        unsigned* __restrict__ qm, unsigned* __restrict__ kb,
        unsigned* __restrict__ vb) {
    unsigned n = *rcnt; if (n > RCAP) n = RCAP;
    unsigned gid = blockIdx.x * 256 + threadIdx.x;
    unsigned stride = gridDim.x * 256;
    for (unsigned e = gid; e < n; e += stride) {
        unsigned ent = rl[e];
        int mb = ent >> 17, s = (ent >> 10) & 127, cg = ent & 1023;
        const float* ar = x + xoff_row(mb, s);
        const float* wc = W + cg;
        float da = 0.f;
#pragma unroll 4
        for (int k4 = 0; k4 < 64; ++k4) {
            float4 a4 = *(const float4*)(ar + k4 * 4);
            da = fmaf(a4.x, wc[(size_t)(k4 * 4 + 0) * NC3], da);
            da = fmaf(a4.y, wc[(size_t)(k4 * 4 + 1) * NC3], da);
            da = fmaf(a4.z, wc[(size_t)(k4 * 4 + 2) * NC3], da);
            da = fmaf(a4.w, wc[(size_t)(k4 * 4 + 3) * NC3], da);
        }
        da += bias[cg];
        int spk = (da >= 2.0f) ? 1 : 0;
        if (cg < 256) {
            int h = cg >> 5, d = cg & 31;
            unsigned* wp = qm + (size_t)mb * 1024 + s * 8 + h;
            unsigned bit = 1u << d;
            int have = (*wp & bit) ? 1 : 0;
            if (have != spk) atomicXor(wp, bit);
        } else {
            unsigned* tgt = (cg < 512) ? kb : vb;
            int c = cg & 255;
            unsigned* wp = tgt + ((size_t)mb * 256 + c) * 4 + (s >> 5);
            unsigned bit = 1u << (s & 31);
            int have = (*wp & bit) ? 1 : 0;
            if (have != spk) atomicXor(wp, bit);
        }
    }
}

// ---- K3.5: column sums of k spikes from bitmasks ----
__global__ __launch_bounds__(256) void kcs_bits(const unsigned* __restrict__ kb,
                                                float* __restrict__ kcs) {
    int g = blockIdx.x;
    int c = threadIdx.x;
    const unsigned* p = kb + ((size_t)g * 256 + c) * 4;
    int acc = __popc(p[0]) + __popc(p[1]) + __popc(p[2]) + __popc(p[3]);
    kcs[g * C_ + c] = (float)acc;
}

// ---- K4: kv[g,h,d,e] = popcount over gathered s-bitmasks (exact int) ----
__global__ __launch_bounds__(256) void kv_bits(const unsigned* __restrict__ kb,
        const unsigned* __restrict__ vb, const int* __restrict__ idx,
        float* __restrict__ kvbuf) {
    int g = blockIdx.x;            // 512
    int tb = g >> 6, n = g & 63, b = tb & 1;
    int tid = threadIdx.x;
    __shared__ uint4 kbl[1024];
    __shared__ uint4 vbl[1024];
    __shared__ int widx[TOPK_];
    if (tid < TOPK_) widx[tid] = idx[(b * 64 + n) * TOPK_ + tid];
    __syncthreads();
#pragma unroll
    for (int kk = 0; kk < TOPK_; ++kk) {
        int g2 = tb * 64 + widx[kk];
        kbl[kk * 256 + tid] = *(const uint4*)&kb[((size_t)g2 * 256 + tid) * 4];
        vbl[kk * 256 + tid] = *(const uint4*)&vb[((size_t)g2 * 256 + tid) * 4];
    }
    __syncthreads();
    int h = tid >> 5, e = tid & 31;
    uint4 vw0 = vbl[0 * 256 + h * 32 + e];
    uint4 vw1 = vbl[1 * 256 + h * 32 + e];
    uint4 vw2 = vbl[2 * 256 + h * 32 + e];
    uint4 vw3 = vbl[3 * 256 + h * 32 + e];
    for (int d = 0; d < 32; ++d) {
        uint4 k0 = kbl[0 * 256 + h * 32 + d];
        uint4 k1 = kbl[1 * 256 + h * 32 + d];
        uint4 k2 = kbl[2 * 256 + h * 32 + d];
        uint4 k3 = kbl[3 * 256 + h * 32 + d];
        int acc = __popc(k0.x & vw0.x) + __popc(k0.y & vw0.y)
                + __popc(k0.z & vw0.z) + __popc(k0.w & vw0.w)
                + __popc(k1.x & vw1.x) + __popc(k1.y & vw1.y)
                + __popc(k1.z & vw1.z) + __popc(k1.w & vw1.w)
                + __popc(k2.x & vw2.x) + __popc(k2.y & vw2.y)
                + __popc(k2.z & vw2.z) + __popc(k2.w & vw2.w)
                + __popc(k3.x & vw3.x) + __popc(k3.y & vw3.y)
                + __popc(k3.z & vw3.z) + __popc(k3.w & vw3.w);
        kvbuf[((size_t)(g * 8 + h) * 32 + d) * 32 + e] = (float)acc;
    }
}

// ---- K5: FUSED attn + proj. One block = ONE window g (all 128 rows),
// qr-loop inside: widx/ksl/qb loaded once; kvbuf read once cold + 3 hot
// passes (was 4 cold blocks). Per-pass body identical to the validated
// per-(g,qr) block body.
__global__ __launch_bounds__(256) void attn_proj(const unsigned* __restrict__ qm,
        const float* __restrict__ kvbuf, const float* __restrict__ kcs,
        const int* __restrict__ idx, const short* __restrict__ Bp,
        const float* __restrict__ bias, float* __restrict__ out) {
    __shared__ __align__(16) short aw[16384];   // 32 KB frags; reused as float ow[32][256]
    __shared__ unsigned qba[1024];
    __shared__ float ksl[256];
    __shared__ int widx[TOPK_];
    const int g = blockIdx.x;          // 512
    const int tb = g >> 6, n = g & 63, b = tb & 1;
    const int tid = threadIdx.x;
    if (tid < TOPK_) widx[tid] = idx[(b * 64 + n) * TOPK_ + tid];
    __syncthreads();
    float ks = 0.f;
#pragma unroll
    for (int kk = 0; kk < TOPK_; ++kk)
        ks += kcs[(size_t)(tb * 64 + widx[kk]) * C_ + tid];
    ksl[tid] = ks;
#pragma unroll
    for (int t = 0; t < 4; ++t)
        qba[t * 256 + tid] = qm[(size_t)g * 1024 + t * 256 + tid];
    __syncthreads();

    const int h = tid >> 5, e = tid & 31;
    float ksr[32];
#pragma unroll
    for (int d = 0; d < 32; ++d) ksr[d] = ksl[h * 32 + d];

    const int ktAh = tid >> 5, ktAl = 8 + (tid >> 5);
    const int octsh = ((tid >> 3) & 3) << 4, sub = tid & 7;
    const int wvw = tid >> 6, lane = tid & 63;
    const int lm = lane & 15, lq = lane >> 4;
    const short* Bb = Bp + ((size_t)(wvw * 4) * 24) * 512 + lane * 8;

    for (int qr = 0; qr < 4; ++qr) {
        // attn: 32 rows -> aw fragments (hi/lo)
        float kvr[32];
#pragma unroll
        for (int d = 0; d < 32; ++d)
            kvr[d] = kvbuf[((size_t)(g * 8 + h) * 32 + d) * 32 + e];
        for (int sl = 0; sl < 32; ++sl) {
            unsigned qw = qba[qr * 256 + sl * 8 + h];
            float r;
            if (qw == 0u) {
                r = 0.f;
            } else {
                float num = 0.f, den = 0.f;
#pragma unroll
                for (int d = 0; d < 32; ++d) {
                    float m = (float)((qw >> d) & 1u);
                    num = fmaf(m, kvr[d], num);
                    den = fmaf(m, ksr[d], den);
                }
                r = num / (den + 1e-6f);
            }
            short hi = f2bf(r), lo = f2bf(r - bf2f(hi));
            int lane2 = (sl & 15) | octsh;
            int gi = sl >> 4;
            aw[((gi * 16 + ktAh) * 64 + lane2) * 8 + sub] = hi;
            aw[((gi * 16 + ktAl) * 64 + lane2) * 8 + sub] = lo;
        }
        __syncthreads();

        // proj: M=32, N=256; 4 waves each N=64
        floatx4 pacc[2][4];
#pragma unroll
        for (int i = 0; i < 2; ++i)
#pragma unroll
            for (int j = 0; j < 4; ++j) pacc[i][j] = (floatx4)0.f;
#pragma unroll 2
        for (int kt = 0; kt < 24; ++kt) {
            int ktA = (kt < 16) ? kt : kt - 16;
            short8 af[2], bf[4];
#pragma unroll
            for (int i = 0; i < 2; ++i)
                af[i] = *(const short8*)&aw[((i * 16 + ktA) * 64 + lane) * 8];
#pragma unroll
            for (int j = 0; j < 4; ++j)
                bf[j] = *(const short8*)(Bb + (size_t)(j * 24 + kt) * 512);
#pragma unroll
            for (int i = 0; i < 2; ++i)
#pragma unroll
                for (int j = 0; j < 4; ++j)
                    pacc[i][j] = __builtin_amdgcn_mfma_f32_16x16x32_bf16(
                        af[i], bf[j], pacc[i][j], 0, 0, 0);
        }
        __syncthreads();

        float* ow = (float*)aw;            // 32 x 256 fp32 rows
#pragma unroll
        for (int i = 0; i < 2; ++i) {
#pragma unroll
            for (int j = 0; j < 4; ++j) {
                int c = wvw * 64 + j * 16 + lm;
                float bj = bias[c];
#pragma unroll
                for (int r = 0; r < 4; ++r)
                    ow[(i * 16 + lq * 4 + r) * 256 + c] = pacc[i][j][r] + bj;
            }
        }
        __syncthreads();

        // coalesced un-windowize store: rows are contiguous 1 KB in out
        int sl2 = tid >> 3, pc = (tid & 7) * 32;
        int off = xoff_row(g, qr * 32 + sl2) + pc;
#pragma unroll
        for (int q = 0; q < 8; ++q)
            *(float4*)(out + off + q * 4) = *(const float4*)&ow[sl2 * 256 + pc + q * 4];
        __syncthreads();   // aw reuse fence for next qr pass
    }
}

extern "C" void kernel_launch(void* const* d_in, const int* in_sizes, int n_in,
                              void* d_out, int out_size, void* d_ws, size_t ws_size,
                              hipStream_t stream) {
    (void)in_sizes; (void)n_in; (void)out_size; (void)ws_size;
    const float* x    = (const float*)d_in[0];
    const float* Wqkv = (const float*)d_in[1];
    const float* bqkv = (const float*)d_in[2];
    const float* Wp   = (const float*)d_in[3];
    const float* bp   = (const float*)d_in[4];
    char* ws = (char*)d_ws;
    short*    A2    = (short*)   (ws + OFF_A2);
    short*    Bq    = (short*)   (ws + OFF_BQ);
    short*    Bpj   = (short*)   (ws + OFF_BP);
    unsigned* qmv   = (unsigned*)(ws + OFF_QM);
    unsigned* kb    = (unsigned*)(ws + OFF_KB);
    unsigned* vb    = (unsigned*)(ws + OFF_VB);
    float*    kvbuf = (float*)   (ws + OFF_KV);
    float*    kcs   = (float*)   (ws + OFF_KCS);
    float*    part  = (float*)   (ws + OFF_PART);
    float*    region= (float*)   (ws + OFF_REGION);
    int*      idxb  = (int*)     (ws + OFF_IDX);
    unsigned* rl    = (unsigned*)(ws + OFF_RL);
    unsigned* rcnt  = (unsigned*)(ws + OFF_RC);
    float*    out   = (float*)d_out;

    hipMemsetAsync(rcnt, 0, 4, stream);
    b_build_qkv    <<<dim3(256, 3), 256, 0, stream>>>(Wqkv, Bq);
    b_build_proj   <<<768, 256, 0, stream>>>(Wp, Bpj);
    k_partial_split<<<512, 256, 0, stream>>>(x, part, A2);
    k_region       <<<128, 256, 0, stream>>>(part, region);
    k_scores       <<<128,  64, 0, stream>>>(region, idxb);
    qkv_mfma       <<<1536, 256, 0, stream>>>(A2, Bq, bqkv, qmv, kb, vb, rl, rcnt);
    rescue_fix     <<<256, 256, 0, stream>>>(x, Wqkv, bqkv, rl, rcnt, qmv, kb, vb);
    kcs_bits       <<<512, 256, 0, stream>>>(kb, kcs);
    kv_bits        <<<512, 256, 0, stream>>>(kb, vb, idxb, kvbuf);
    attn_proj      <<<512, 256, 0, stream>>>(qmv, kvbuf, kcs, idxb, Bpj, bp, out);
}

// Round 6
// 248.503 us; speedup vs baseline: 1.4266x; 1.0950x over previous
//
#include <hip/hip_runtime.h>
#include <cstdint>
#include <cstddef>

// Problem constants (fixed by reference shapes)
#define T_    4
#define B_    2
#define NW_   64
#define WS_   128
#define C_    256
#define NC3   768
#define H_    8
#define HD_   32
#define TOPK_ 4
#define RCAP  131072
#define BAND  0.008f
#define RBCAP 512          // per-block LDS rescue staging capacity

// Workspace layout (bytes, all 16B aligned). Total ~92.7 MB.
// A2/Bq/Bp are stored FRAGMENT-MAJOR: the exact 16x16x32-bf16 MFMA operand
// register layout (lane = (m|n)&15 | octet<<4, 8 contiguous shorts per lane),
// so GEMM kernels load operands straight into VGPRs -> no LDS, no K-loop
// barriers.
// qkv GEMM is 2-TERM bf16x2 (A_hi*W_hi + A_lo*W_hi). Dropped-term error
// sigma ~= 1.1e-3; band 0.008 = 7.1 sigma. Borderline outputs -> rescue.
// Rescue append is LDS-staged per block + ONE global atomicAdd per block
// (R2 lesson: 40K same-address device atomics serialize at one L2 bank).
// R4 lesson: in-block p-loop => compiler unrolls trip-3 and spills acc.
// R5 lesson: attn_proj qr-fold regressed (lost cross-block phase overlap);
// attn_proj stays at the validated 2048-block version.
// R6: qkv wave tile halved to acc[2][8] (64 AGPR) so regalloc fits 3
// waves/SIMD (was 2 at 256 regs/wave) -> +50% TLP for the latency chain.
#define OFF_A2     0ull            // [mb][gi 0..7][ktA 0..15][lane][8] = 64 MB
#define OFF_BQ     67108864ull     // [gj 0..47][ktB 0..7][lane][8] = 393,216 (hi only)
#define OFF_BP     67502080ull     // [gj 0..15][ktB 0..23][lane][8] = 393,216 (3-term)
#define OFF_QM     67895296ull     // qmask u32 [g][s][h] = 2,097,152
#define OFF_KB     69992448ull     // 2,097,152
#define OFF_VB     72089600ull     // 2,097,152
#define OFF_KV     74186752ull     // 16,777,216
#define OFF_KCS    90963968ull     // 524,288
#define OFF_PART   91488256ull     // 524,288
#define OFF_REGION 92012544ull     // 131,072
#define OFF_IDX    92143616ull     // 2,048
#define OFF_RL     92145664ull     // 524,288 (131072 entries)
#define OFF_RC     92669952ull     // 16

typedef short short8 __attribute__((ext_vector_type(8)));
typedef float floatx4 __attribute__((ext_vector_type(4)));

__device__ __forceinline__ short f2bf(float f) {
    unsigned u = __float_as_uint(f);
    unsigned r = (u + 0x7fffu + ((u >> 16) & 1u)) >> 16;
    return (short)r;
}
__device__ __forceinline__ float bf2f(short h) {
    return __uint_as_float(((unsigned)(unsigned short)h) << 16);
}

// g = (t*B_+b)*NW_ + n, s in [0,128): float index of x[t,b,lt,lh,lw,0]
__device__ __forceinline__ int xoff_row(int g, int s) {
    int tb = g >> 6;
    int n  = g & 63;
    int iwt = n >> 4, iwh = (n >> 2) & 3, iww = n & 3;
    int ipt = s >> 6, iph = (s >> 3) & 7, ipw = s & 7;
    int lt = iwt * 2 + ipt, lh = iwh * 8 + iph, lw = iww * 8 + ipw;
    return (((tb * 8 + lt) * 32 + lh) * 32 + lw) * 256;
}

// ---- K1a: partial sums + write A2 in fragment-major bf16 hi/lo ----
__global__ __launch_bounds__(256) void k_partial_split(const float* __restrict__ x,
        float* __restrict__ part, short* __restrict__ A2) {
    int g = blockIdx.x;            // 512
    int c = threadIdx.x;
    const int ktAh = c >> 5, ktAl = 8 + (c >> 5);
    const int octsh = ((c >> 3) & 3) << 4, sub = c & 7;
    float acc = 0.f;
    for (int s = 0; s < WS_; ++s) {
        float v = x[xoff_row(g, s) + c];
        acc += v;
        short hi = f2bf(v);
        short lo = f2bf(v - bf2f(hi));
        int lane = (s & 15) | octsh;
        size_t base = ((size_t)(g * 8 + (s >> 4))) * 16;
        A2[(base + ktAh) * 512 + lane * 8 + sub] = hi;
        A2[(base + ktAl) * 512 + lane * 8 + sub] = lo;
    }
    part[g * C_ + c] = acc;
}

// ---- K1b: region[b,n,c] = sum_t part / 128 ----
__global__ __launch_bounds__(256) void k_region(const float* __restrict__ part,
                                                float* __restrict__ region) {
    int bn = blockIdx.x;           // 128
    int c = threadIdx.x;
    int b = bn >> 6, n = bn & 63;
    float acc = 0.f;
    for (int t = 0; t < T_; ++t) acc += part[((t * 2 + b) * 64 + n) * C_ + c];
    region[bn * C_ + c] = acc * (1.0f / 128.0f);
}

// ---- K2: scores + top-4 (lowest-index tie-break) ----
__global__ __launch_bounds__(64) void k_scores(const float* __restrict__ region,
                                               int* __restrict__ idx) {
    int bi = blockIdx.x;           // 128
    int b = bi >> 6, i = bi & 63;
    int tid = threadIdx.x;
    __shared__ float ri[C_];
    __shared__ float sc[64];
    for (int c = tid; c < C_; c += 64) ri[c] = region[(b * 64 + i) * C_ + c];
    __syncthreads();
    const float* rj = region + (size_t)(b * 64 + tid) * C_;
    float dot = 0.f;
    for (int c = 0; c < C_; ++c) dot += ri[c] * rj[c];
    sc[tid] = dot * 0.17677669529663687f;
    __syncthreads();
    if (tid == 0) {
        for (int kk = 0; kk < TOPK_; ++kk) {
            float best = -INFINITY; int bj = 0;
            for (int j = 0; j < 64; ++j)
                if (sc[j] > best) { best = sc[j]; bj = j; }
            idx[bi * TOPK_ + kk] = bj;
            sc[bj] = -INFINITY;
        }
    }
}

// ---- B' builders, fragment-major ----
// Bq: hi(W) only, 8 k-tiles (2-term scheme shares B between A_hi and A_lo).
__global__ __launch_bounds__(256) void b_build_qkv(const float* __restrict__ W,
                                                   short* __restrict__ Bq) {
    int ke = blockIdx.x;                     // 0..255 (hi only)
    int n = blockIdx.y * 256 + threadIdx.x;  // 0..767
    float wv = W[(size_t)ke * NC3 + n];
    short o = f2bf(wv);
    int gj = n >> 4, lmn = n & 15, ktB = ke >> 5, oct = (ke >> 3) & 3, sub = ke & 7;
    Bq[(size_t)((gj * 8 + ktB) * 64 + (lmn | (oct << 4))) * 8 + sub] = o;
}
// Bp: 3-term [hi | hi | lo], 24 k-tiles (proj must stay exact to tolerance).
__global__ __launch_bounds__(256) void b_build_proj(const float* __restrict__ W,
                                                    short* __restrict__ Bp) {
    int ke = blockIdx.x;                // 0..767
    int n = threadIdx.x;                // 0..255
    float wv = W[(size_t)(ke & 255) * 256 + n];
    short hi = f2bf(wv);
    short o = (ke < 512) ? hi : f2bf(wv - bf2f(hi));
    int gj = n >> 4, lmn = n & 15, ktB = ke >> 5, oct = (ke >> 3) & 3, sub = ke & 7;
    Bp[(size_t)((gj * 24 + ktB) * 64 + (lmn | (oct << 4))) * 8 + sub] = o;
}

__device__ __forceinline__ unsigned p4(unsigned xv) {
    return (xv & 1u) | ((xv >> 7) & 2u) | ((xv >> 14) & 4u) | ((xv >> 21) & 8u);
}

// ---- K3: qkv GEMM, fragment-direct (NO LDS in K-loop, NO barriers).
// Wave tile M=32 x N=128 (acc[2][8] = 64 AGPR); block M=64 x N=256.
// grid 3072: bid -> (mb, mhalf, p); all 6 blocks of one mb share bid%8
// (same XCD) and are dispatch-adjacent. Per-output MFMA order identical
// to R3 (ah then al per ktB) -> bit-identical numerics.
__global__ __launch_bounds__(256, 3) void qkv_mfma(const short* __restrict__ A2,
        const short* __restrict__ Bq, const float* __restrict__ bias,
        unsigned* __restrict__ qm, unsigned* __restrict__ kb,
        unsigned* __restrict__ vb, unsigned* __restrict__ rl,
        unsigned* __restrict__ rcnt) {
    __shared__ unsigned char sp[64 * 264];
    __shared__ unsigned rbuf[RBCAP];
    __shared__ unsigned lcnt, sbase;
    const int bid = blockIdx.x;            // 0..3071
    const int x8 = bid & 7;
    const int y = bid >> 3;                // 0..383
    const int p = y % 3;
    const int rest = y / 3;                // 0..127
    const int mhalf = rest & 1;
    const int mb = x8 + ((rest >> 1) << 3);
    const int tid = threadIdx.x;
    const int wv = tid >> 6, lane = tid & 63;
    const int wm = wv >> 1, wn = wv & 1;
    const int lm = lane & 15, lq = lane >> 4;

    if (tid == 0) lcnt = 0;
    __syncthreads();

    floatx4 acc[2][8];
#pragma unroll
    for (int i = 0; i < 2; ++i)
#pragma unroll
        for (int j = 0; j < 8; ++j) acc[i][j] = (floatx4)0.f;

    // gi = mhalf*4 + wm*2 + i  (i in 0..2)
    const short* Ab = A2 + ((size_t)(mb * 8 + mhalf * 4 + wm * 2) * 16) * 512 + lane * 8;
    const short* Bb = Bq + ((size_t)(p * 16 + wn * 8) * 8) * 512 + lane * 8;

    for (int ktB = 0; ktB < 8; ++ktB) {
        short8 ah[2], al[2], bf[8];
#pragma unroll
        for (int j = 0; j < 8; ++j)
            bf[j] = *(const short8*)(Bb + (size_t)(j * 8 + ktB) * 512);
#pragma unroll
        for (int i = 0; i < 2; ++i) {
            ah[i] = *(const short8*)(Ab + (size_t)(i * 16 + ktB) * 512);
            al[i] = *(const short8*)(Ab + (size_t)(i * 16 + 8 + ktB) * 512);
        }
#pragma unroll
        for (int i = 0; i < 2; ++i)
#pragma unroll
            for (int j = 0; j < 8; ++j)
                acc[i][j] = __builtin_amdgcn_mfma_f32_16x16x32_bf16(
                    ah[i], bf[j], acc[i][j], 0, 0, 0);
#pragma unroll
        for (int i = 0; i < 2; ++i)
#pragma unroll
            for (int j = 0; j < 8; ++j)
                acc[i][j] = __builtin_amdgcn_mfma_f32_16x16x32_bf16(
                    al[i], bf[j], acc[i][j], 0, 0, 0);
    }

    // epilogue: spikes into LDS (64 local s-rows); borderline -> rescue staging
#pragma unroll
    for (int i = 0; i < 2; ++i) {
#pragma unroll
        for (int j = 0; j < 8; ++j) {
            int cb = wn * 128 + j * 16 + lm;
            int cg = p * 256 + cb;
            float bj = bias[cg];
#pragma unroll
            for (int r = 0; r < 4; ++r) {
                int sl = wm * 32 + i * 16 + lq * 4 + r;       // local 0..63
                int s  = mhalf * 64 + sl;                     // global 0..127
                float v = acc[i][j][r] + bj;
                if (fabsf(v - 2.0f) < BAND) {
                    unsigned ent = ((unsigned)mb << 17) | ((unsigned)s << 10) | (unsigned)cg;
                    unsigned slot = atomicAdd(&lcnt, 1u);
                    if (slot < RBCAP) {
                        rbuf[slot] = ent;
                    } else {                       // overflow fallback (cold)
                        unsigned gs = atomicAdd(rcnt, 1u);
                        if (gs < RCAP) rl[gs] = ent;
                    }
                }
                sp[sl * 264 + cb] = (v >= 2.0f) ? 1 : 0;
            }
        }
    }
    __syncthreads();

    // bulk-reserve rescue slots: ONE global atomic per block
    unsigned cnt = lcnt;
    if (cnt > RBCAP) cnt = RBCAP;
    if (tid == 0) sbase = atomicAdd(rcnt, cnt);
    __syncthreads();
    for (unsigned e = tid; e < cnt; e += 256) {
        unsigned slot = sbase + e;
        if (slot < RCAP) rl[slot] = rbuf[e];
    }

    if (p == 0) {
        // pack q bitmasks: qm[g][s][h], this block's 64 s-rows = 512 words
        const unsigned* spw = (const unsigned*)sp;   // pitch 66 words
#pragma unroll
        for (int t = 0; t < 2; ++t) {
            int w = t * 256 + tid;                   // 0..511
            int sl = w >> 3, h = w & 7;
            unsigned m = 0;
#pragma unroll
            for (int q = 0; q < 8; ++q)
                m |= p4(spw[sl * 66 + h * 8 + q]) << (q * 4);
            qm[(size_t)mb * 1024 + (mhalf * 64 + sl) * 8 + h] = m;
        }
    } else {
        // pack k/v bitmasks along s: 2 words (this mhalf) per channel
        unsigned wrd[2];
#pragma unroll
        for (int w2 = 0; w2 < 2; ++w2) {
            unsigned m = 0;
#pragma unroll
            for (int ii = 0; ii < 32; ++ii)
                m |= (unsigned)(sp[(w2 * 32 + ii) * 264 + tid] & 1) << ii;
            wrd[w2] = m;
        }
        uint2 o; o.x = wrd[0]; o.y = wrd[1];
        *(uint2*)(((p == 1) ? kb : vb) + ((size_t)mb * 256 + tid) * 4 + mhalf * 2) = o;
    }
}

// ---- rescue: LANE-PARALLEL serial ascending-k fp32 FMA per entry.
// Per-entry summation order identical to the validated serial rescue.
__global__ __launch_bounds__(256) void rescue_fix(const float* __restrict__ x,
        const float* __restrict__ W, const float* __restrict__ bias,
        const unsigned* __restrict__ rl, const unsigned* __restrict__ rcnt,
        unsigned* __restrict__ qm, unsigned* __restrict__ kb,
        unsigned* __restrict__ vb) {
    unsigned n = *rcnt; if (n > RCAP) n = RCAP;
    unsigned gid = blockIdx.x * 256 + threadIdx.x;
    unsigned stride = gridDim.x * 256;
    for (unsigned e = gid; e < n; e += stride) {
        unsigned ent = rl[e];
        int mb = ent >> 17, s = (ent >> 10) & 127, cg = ent & 1023;
        const float* ar = x + xoff_row(mb, s);
        const float* wc = W + cg;
        float da = 0.f;
#pragma unroll 4
        for (int k4 = 0; k4 < 64; ++k4) {
            float4 a4 = *(const float4*)(ar + k4 * 4);
            da = fmaf(a4.x, wc[(size_t)(k4 * 4 + 0) * NC3], da);
            da = fmaf(a4.y, wc[(size_t)(k4 * 4 + 1) * NC3], da);
            da = fmaf(a4.z, wc[(size_t)(k4 * 4 + 2) * NC3], da);
            da = fmaf(a4.w, wc[(size_t)(k4 * 4 + 3) * NC3], da);
        }
        da += bias[cg];
        int spk = (da >= 2.0f) ? 1 : 0;
        if (cg < 256) {
            int h = cg >> 5, d = cg & 31;
            unsigned* wp = qm + (size_t)mb * 1024 + s * 8 + h;
            unsigned bit = 1u << d;
            int have = (*wp & bit) ? 1 : 0;
            if (have != spk) atomicXor(wp, bit);
        } else {
            unsigned* tgt = (cg < 512) ? kb : vb;
            int c = cg & 255;
            unsigned* wp = tgt + ((size_t)mb * 256 + c) * 4 + (s >> 5);
            unsigned bit = 1u << (s & 31);
            int have = (*wp & bit) ? 1 : 0;
            if (have != spk) atomicXor(wp, bit);
        }
    }
}

// ---- K3.5: column sums of k spikes from bitmasks ----
__global__ __launch_bounds__(256) void kcs_bits(const unsigned* __restrict__ kb,
                                                float* __restrict__ kcs) {
    int g = blockIdx.x;
    int c = threadIdx.x;
    const unsigned* p = kb + ((size_t)g * 256 + c) * 4;
    int acc = __popc(p[0]) + __popc(p[1]) + __popc(p[2]) + __popc(p[3]);
    kcs[g * C_ + c] = (float)acc;
}

// ---- K4: kv[g,h,d,e] = popcount over gathered s-bitmasks (exact int) ----
__global__ __launch_bounds__(256) void kv_bits(const unsigned* __restrict__ kb,
        const unsigned* __restrict__ vb, const int* __restrict__ idx,
        float* __restrict__ kvbuf) {
    int g = blockIdx.x;            // 512
    int tb = g >> 6, n = g & 63, b = tb & 1;
    int tid = threadIdx.x;
    __shared__ uint4 kbl[1024];
    __shared__ uint4 vbl[1024];
    __shared__ int widx[TOPK_];
    if (tid < TOPK_) widx[tid] = idx[(b * 64 + n) * TOPK_ + tid];
    __syncthreads();
#pragma unroll
    for (int kk = 0; kk < TOPK_; ++kk) {
        int g2 = tb * 64 + widx[kk];
        kbl[kk * 256 + tid] = *(const uint4*)&kb[((size_t)g2 * 256 + tid) * 4];
        vbl[kk * 256 + tid] = *(const uint4*)&vb[((size_t)g2 * 256 + tid) * 4];
    }
    __syncthreads();
    int h = tid >> 5, e = tid & 31;
    uint4 vw0 = vbl[0 * 256 + h * 32 + e];
    uint4 vw1 = vbl[1 * 256 + h * 32 + e];
    uint4 vw2 = vbl[2 * 256 + h * 32 + e];
    uint4 vw3 = vbl[3 * 256 + h * 32 + e];
    for (int d = 0; d < 32; ++d) {
        uint4 k0 = kbl[0 * 256 + h * 32 + d];
        uint4 k1 = kbl[1 * 256 + h * 32 + d];
        uint4 k2 = kbl[2 * 256 + h * 32 + d];
        uint4 k3 = kbl[3 * 256 + h * 32 + d];
        int acc = __popc(k0.x & vw0.x) + __popc(k0.y & vw0.y)
                + __popc(k0.z & vw0.z) + __popc(k0.w & vw0.w)
                + __popc(k1.x & vw1.x) + __popc(k1.y & vw1.y)
                + __popc(k1.z & vw1.z) + __popc(k1.w & vw1.w)
                + __popc(k2.x & vw2.x) + __popc(k2.y & vw2.y)
                + __popc(k2.z & vw2.z) + __popc(k2.w & vw2.w)
                + __popc(k3.x & vw3.x) + __popc(k3.y & vw3.y)
                + __popc(k3.z & vw3.z) + __popc(k3.w & vw3.w);
        kvbuf[((size_t)(g * 8 + h) * 32 + d) * 32 + e] = (float)acc;
    }
}

// ---- K5: FUSED attn + proj. One block = 32 rows of one window g. ----
// (Exact R3 version: validated 2048-block structure.)
__global__ __launch_bounds__(256) void attn_proj(const unsigned* __restrict__ qm,
        const float* __restrict__ kvbuf, const float* __restrict__ kcs,
        const int* __restrict__ idx, const short* __restrict__ Bp,
        const float* __restrict__ bias, float* __restrict__ out) {
    __shared__ __align__(16) short aw[16384];   // 32 KB frags; reused as float ow[32][256]
    __shared__ unsigned qb[256];
    __shared__ float ksl[256];
    __shared__ int widx[TOPK_];
    const int bid = blockIdx.x;        // 2048
    const int g = bid >> 2, qr = bid & 3;
    const int tb = g >> 6, n = g & 63, b = tb & 1;
    const int tid = threadIdx.x;
    if (tid < TOPK_) widx[tid] = idx[(b * 64 + n) * TOPK_ + tid];
    __syncthreads();
    float ks = 0.f;
#pragma unroll
    for (int kk = 0; kk < TOPK_; ++kk)
        ks += kcs[(size_t)(tb * 64 + widx[kk]) * C_ + tid];
    ksl[tid] = ks;
    qb[tid] = qm[(size_t)g * 1024 + qr * 256 + tid];
    __syncthreads();

    const int h = tid >> 5, e = tid & 31;
    float kvr[32], ksr[32];
#pragma unroll
    for (int d = 0; d < 32; ++d)
        kvr[d] = kvbuf[((size_t)(g * 8 + h) * 32 + d) * 32 + e];
#pragma unroll
    for (int d = 0; d < 32; ++d) ksr[d] = ksl[h * 32 + d];

    const int ktAh = tid >> 5, ktAl = 8 + (tid >> 5);
    const int octsh = ((tid >> 3) & 3) << 4, sub = tid & 7;
    for (int sl = 0; sl < 32; ++sl) {
        unsigned qw = qb[sl * 8 + h];
        float r;
        if (qw == 0u) {
            r = 0.f;
        } else {
            float num = 0.f, den = 0.f;
#pragma unroll
            for (int d = 0; d < 32; ++d) {
                float m = (float)((qw >> d) & 1u);
                num = fmaf(m, kvr[d], num);
                den = fmaf(m, ksr[d], den);
            }
            r = num / (den + 1e-6f);
        }
        short hi = f2bf(r), lo = f2bf(r - bf2f(hi));
        int lane2 = (sl & 15) | octsh;
        int gi = sl >> 4;
        aw[((gi * 16 + ktAh) * 64 + lane2) * 8 + sub] = hi;
        aw[((gi * 16 + ktAl) * 64 + lane2) * 8 + sub] = lo;
    }
    __syncthreads();

    // proj: M=32, N=256; 4 waves each N=64
    const int wvw = tid >> 6, lane = tid & 63;
    const int lm = lane & 15, lq = lane >> 4;
    floatx4 pacc[2][4];
#pragma unroll
    for (int i = 0; i < 2; ++i)
#pragma unroll
        for (int j = 0; j < 4; ++j) pacc[i][j] = (floatx4)0.f;
    const short* Bb = Bp + ((size_t)(wvw * 4) * 24) * 512 + lane * 8;
#pragma unroll 2
    for (int kt = 0; kt < 24; ++kt) {
        int ktA = (kt < 16) ? kt : kt - 16;
        short8 af[2], bf[4];
#pragma unroll
        for (int i = 0; i < 2; ++i)
            af[i] = *(const short8*)&aw[((i * 16 + ktA) * 64 + lane) * 8];
#pragma unroll
        for (int j = 0; j < 4; ++j)
            bf[j] = *(const short8*)(Bb + (size_t)(j * 24 + kt) * 512);
#pragma unroll
        for (int i = 0; i < 2; ++i)
#pragma unroll
            for (int j = 0; j < 4; ++j)
                pacc[i][j] = __builtin_amdgcn_mfma_f32_16x16x32_bf16(
                    af[i], bf[j], pacc[i][j], 0, 0, 0);
    }
    __syncthreads();

    float* ow = (float*)aw;            // 32 x 256 fp32 rows
#pragma unroll
    for (int i = 0; i < 2; ++i) {
#pragma unroll
        for (int j = 0; j < 4; ++j) {
            int c = wvw * 64 + j * 16 + lm;
            float bj = bias[c];
#pragma unroll
            for (int r = 0; r < 4; ++r)
                ow[(i * 16 + lq * 4 + r) * 256 + c] = pacc[i][j][r] + bj;
        }
    }
    __syncthreads();

    // coalesced un-windowize store: rows are contiguous 1 KB in out
    int sl2 = tid >> 3, pc = (tid & 7) * 32;
    int off = xoff_row(g, qr * 32 + sl2) + pc;
#pragma unroll
    for (int q = 0; q < 8; ++q)
        *(float4*)(out + off + q * 4) = *(const float4*)&ow[sl2 * 256 + pc + q * 4];
}

extern "C" void kernel_launch(void* const* d_in, const int* in_sizes, int n_in,
                              void* d_out, int out_size, void* d_ws, size_t ws_size,
                              hipStream_t stream) {
    (void)in_sizes; (void)n_in; (void)out_size; (void)ws_size;
    const float* x    = (const float*)d_in[0];
    const float* Wqkv = (const float*)d_in[1];
    const float* bqkv = (const float*)d_in[2];
    const float* Wp   = (const float*)d_in[3];
    const float* bp   = (const float*)d_in[4];
    char* ws = (char*)d_ws;
    short*    A2    = (short*)   (ws + OFF_A2);
    short*    Bq    = (short*)   (ws + OFF_BQ);
    short*    Bpj   = (short*)   (ws + OFF_BP);
    unsigned* qmv   = (unsigned*)(ws + OFF_QM);
    unsigned* kb    = (unsigned*)(ws + OFF_KB);
    unsigned* vb    = (unsigned*)(ws + OFF_VB);
    float*    kvbuf = (float*)   (ws + OFF_KV);
    float*    kcs   = (float*)   (ws + OFF_KCS);
    float*    part  = (float*)   (ws + OFF_PART);
    float*    region= (float*)   (ws + OFF_REGION);
    int*      idxb  = (int*)     (ws + OFF_IDX);
    unsigned* rl    = (unsigned*)(ws + OFF_RL);
    unsigned* rcnt  = (unsigned*)(ws + OFF_RC);
    float*    out   = (float*)d_out;

    hipMemsetAsync(rcnt, 0, 4, stream);
    b_build_qkv    <<<dim3(256, 3), 256, 0, stream>>>(Wqkv, Bq);
    b_build_proj   <<<768, 256, 0, stream>>>(Wp, Bpj);
    k_partial_split<<<512, 256, 0, stream>>>(x, part, A2);
    k_region       <<<128, 256, 0, stream>>>(part, region);
    k_scores       <<<128,  64, 0, stream>>>(region, idxb);
    qkv_mfma       <<<3072, 256, 0, stream>>>(A2, Bq, bqkv, qmv, kb, vb, rl, rcnt);
    rescue_fix     <<<256, 256, 0, stream>>>(x, Wqkv, bqkv, rl, rcnt, qmv, kb, vb);
    kcs_bits       <<<512, 256, 0, stream>>>(kb, kcs);
    kv_bits        <<<512, 256, 0, stream>>>(kb, vb, idxb, kvbuf);
    attn_proj      <<<2048, 256, 0, stream>>>(qmv, kvbuf, kcs, idxb, Bpj, bp, out);
}

// Round 7
// 235.913 us; speedup vs baseline: 1.5028x; 1.0534x over previous
//
#include <hip/hip_runtime.h>
#include <cstdint>
#include <cstddef>

// Problem constants (fixed by reference shapes)
#define T_    4
#define B_    2
#define NW_   64
#define WS_   128
#define C_    256
#define NC3   768
#define H_    8
#define HD_   32
#define TOPK_ 4
#define RCAP  131072
#define BAND  0.008f
#define RBCAP 512          // per-block LDS rescue staging capacity

// Workspace layout (bytes, all 16B aligned). Total ~92.7 MB.
// A2/Bq/Bp are stored FRAGMENT-MAJOR: the exact 16x16x32-bf16 MFMA operand
// register layout (lane = (m|n)&15 | octet<<4, 8 contiguous shorts per lane).
// qkv GEMM is 2-TERM bf16x2 (A_hi*W_hi + A_lo*W_hi); band 0.008 = 7.1 sigma;
// borderline outputs go to the lane-parallel serial-fp32 rescue.
// R2 lesson: same-address device atomics serialize; rescue is LDS-staged.
// R4 lesson: in-block p-loop => acc spill to scratch.
// R5 lesson: attn_proj qr-fold regressed; stays at 2048-block version.
// R6 lesson: occupancy 21->31% moved qkv only 102->95us -> not TLP-bound.
// R7: qkv feed traffic was the wall (A fetched 2x/block from L3 [64MB misses
// L2], B 4x/block from L2). Stage A+B chunks into LDS ONCE per block via
// global_load_lds (async DMA queue), waves read fragments via ds_read_b128.
// m97-pattern: stage(next) -> compute(cur) -> __syncthreads.
#define OFF_A2     0ull            // [mb][gi 0..7][ktA 0..15][lane][8] = 64 MB
#define OFF_BQ     67108864ull     // [gj 0..47][ktB 0..7][lane][8] = 393,216 (hi only)
#define OFF_BP     67502080ull     // [gj 0..15][ktB 0..23][lane][8] = 393,216 (3-term)
#define OFF_QM     67895296ull     // qmask u32 [g][s][h] = 2,097,152
#define OFF_KB     69992448ull     // 2,097,152
#define OFF_VB     72089600ull     // 2,097,152
#define OFF_KV     74186752ull     // 16,777,216
#define OFF_KCS    90963968ull     // 524,288
#define OFF_PART   91488256ull     // 524,288
#define OFF_REGION 92012544ull     // 131,072
#define OFF_IDX    92143616ull     // 2,048
#define OFF_RL     92145664ull     // 524,288 (131072 entries)
#define OFF_RC     92669952ull     // 16

typedef short short8 __attribute__((ext_vector_type(8)));
typedef float floatx4 __attribute__((ext_vector_type(4)));

__device__ __forceinline__ short f2bf(float f) {
    unsigned u = __float_as_uint(f);
    unsigned r = (u + 0x7fffu + ((u >> 16) & 1u)) >> 16;
    return (short)r;
}
__device__ __forceinline__ float bf2f(short h) {
    return __uint_as_float(((unsigned)(unsigned short)h) << 16);
}

__device__ __forceinline__ void gload_lds16(const void* g, void* l) {
    __builtin_amdgcn_global_load_lds(
        (const __attribute__((address_space(1))) unsigned*)g,
        (__attribute__((address_space(3))) unsigned*)l,
        16, 0, 0);
}

// g = (t*B_+b)*NW_ + n, s in [0,128): float index of x[t,b,lt,lh,lw,0]
__device__ __forceinline__ int xoff_row(int g, int s) {
    int tb = g >> 6;
    int n  = g & 63;
    int iwt = n >> 4, iwh = (n >> 2) & 3, iww = n & 3;
    int ipt = s >> 6, iph = (s >> 3) & 7, ipw = s & 7;
    int lt = iwt * 2 + ipt, lh = iwh * 8 + iph, lw = iww * 8 + ipw;
    return (((tb * 8 + lt) * 32 + lh) * 32 + lw) * 256;
}

// ---- K1a: partial sums + write A2 in fragment-major bf16 hi/lo ----
__global__ __launch_bounds__(256) void k_partial_split(const float* __restrict__ x,
        float* __restrict__ part, short* __restrict__ A2) {
    int g = blockIdx.x;            // 512
    int c = threadIdx.x;
    const int ktAh = c >> 5, ktAl = 8 + (c >> 5);
    const int octsh = ((c >> 3) & 3) << 4, sub = c & 7;
    float acc = 0.f;
    for (int s = 0; s < WS_; ++s) {
        float v = x[xoff_row(g, s) + c];
        acc += v;
        short hi = f2bf(v);
        short lo = f2bf(v - bf2f(hi));
        int lane = (s & 15) | octsh;
        size_t base = ((size_t)(g * 8 + (s >> 4))) * 16;
        A2[(base + ktAh) * 512 + lane * 8 + sub] = hi;
        A2[(base + ktAl) * 512 + lane * 8 + sub] = lo;
    }
    part[g * C_ + c] = acc;
}

// ---- K1b: region[b,n,c] = sum_t part / 128 ----
__global__ __launch_bounds__(256) void k_region(const float* __restrict__ part,
                                                float* __restrict__ region) {
    int bn = blockIdx.x;           // 128
    int c = threadIdx.x;
    int b = bn >> 6, n = bn & 63;
    float acc = 0.f;
    for (int t = 0; t < T_; ++t) acc += part[((t * 2 + b) * 64 + n) * C_ + c];
    region[bn * C_ + c] = acc * (1.0f / 128.0f);
}

// ---- K2: scores + top-4 (lowest-index tie-break) ----
__global__ __launch_bounds__(64) void k_scores(const float* __restrict__ region,
                                               int* __restrict__ idx) {
    int bi = blockIdx.x;           // 128
    int b = bi >> 6, i = bi & 63;
    int tid = threadIdx.x;
    __shared__ float ri[C_];
    __shared__ float sc[64];
    for (int c = tid; c < C_; c += 64) ri[c] = region[(b * 64 + i) * C_ + c];
    __syncthreads();
    const float* rj = region + (size_t)(b * 64 + tid) * C_;
    float dot = 0.f;
    for (int c = 0; c < C_; ++c) dot += ri[c] * rj[c];
    sc[tid] = dot * 0.17677669529663687f;
    __syncthreads();
    if (tid == 0) {
        for (int kk = 0; kk < TOPK_; ++kk) {
            float best = -INFINITY; int bj = 0;
            for (int j = 0; j < 64; ++j)
                if (sc[j] > best) { best = sc[j]; bj = j; }
            idx[bi * TOPK_ + kk] = bj;
            sc[bj] = -INFINITY;
        }
    }
}

// ---- B' builders, fragment-major ----
// Bq: hi(W) only, 8 k-tiles (2-term scheme shares B between A_hi and A_lo).
__global__ __launch_bounds__(256) void b_build_qkv(const float* __restrict__ W,
                                                   short* __restrict__ Bq) {
    int ke = blockIdx.x;                     // 0..255 (hi only)
    int n = blockIdx.y * 256 + threadIdx.x;  // 0..767
    float wv = W[(size_t)ke * NC3 + n];
    short o = f2bf(wv);
    int gj = n >> 4, lmn = n & 15, ktB = ke >> 5, oct = (ke >> 3) & 3, sub = ke & 7;
    Bq[(size_t)((gj * 8 + ktB) * 64 + (lmn | (oct << 4))) * 8 + sub] = o;
}
// Bp: 3-term [hi | hi | lo], 24 k-tiles (proj must stay exact to tolerance).
__global__ __launch_bounds__(256) void b_build_proj(const float* __restrict__ W,
                                                    short* __restrict__ Bp) {
    int ke = blockIdx.x;                // 0..767
    int n = threadIdx.x;                // 0..255
    float wv = W[(size_t)(ke & 255) * 256 + n];
    short hi = f2bf(wv);
    short o = (ke < 512) ? hi : f2bf(wv - bf2f(hi));
    int gj = n >> 4, lmn = n & 15, ktB = ke >> 5, oct = (ke >> 3) & 3, sub = ke & 7;
    Bp[(size_t)((gj * 24 + ktB) * 64 + (lmn | (oct << 4))) * 8 + sub] = o;
}

__device__ __forceinline__ unsigned p4(unsigned xv) {
    return (xv & 1u) | ((xv >> 7) & 2u) | ((xv >> 14) & 4u) | ((xv >> 21) & 8u);
}

// ---- K3: qkv GEMM, LDS-staged (m97 pattern).
// Block = (mb, p): M=128, N=256. Per ktB chunk (32 KB): [0,16K) = A
// [gi 0..7][hi|lo][1KB], [16K,32K) = B [gj' 0..15][1KB]. Staged by 8
// global_load_lds(16B) per thread: k=0..3 -> A (slot = k*4+wv uniform/instr,
// dest = uniform + lane*16), k=4..7 -> B. Double-buffered; stage(next) ->
// ds_read+MFMA(cur) -> __syncthreads. MFMA order per output identical to
// R3/R6 (ah then al per ktB) -> bit-identical numerics.
__global__ __launch_bounds__(256, 2) void qkv_mfma(const short* __restrict__ A2,
        const short* __restrict__ Bq, const float* __restrict__ bias,
        unsigned* __restrict__ qm, unsigned* __restrict__ kb,
        unsigned* __restrict__ vb, unsigned* __restrict__ rl,
        unsigned* __restrict__ rcnt) {
    __shared__ __align__(16) char stg[2][32768];   // staging; [0] reused as sp
    __shared__ unsigned rbuf[RBCAP];
    __shared__ unsigned lcnt, sbase;
    const int bid = blockIdx.x;            // 0..1535
    const int x8 = bid & 7;
    const int y = bid >> 3;                // 0..191
    const int p = y % 3;
    const int mb = x8 + ((y / 3) << 3);    // bijective: all (mb,p) covered
    const int tid = threadIdx.x;
    const int wv = tid >> 6, lane = tid & 63;
    const int wm = wv >> 1, wn = wv & 1;
    const int lm = lane & 15, lq = lane >> 4;

    if (tid == 0) lcnt = 0;

    const char* Ag = (const char*)(A2 + (size_t)mb * 65536);   // 128 KB slice
    const char* Bg = (const char*)(Bq + (size_t)p * 65536);    // 128 KB slice
    const int laneoff = lane * 16;

    // ---- stage chunk ktB into stg[buf] ----
    // k=0..3: A slot = k*4+wv (gi = slot>>1, hl = slot&1), kt = ktB + hl*8
    // k=4..7: B slot = (k-4)*4+wv (gj'), row ktB
#define STAGE_CHUNK(buf, ktB_)                                                 \
    {                                                                          \
        _Pragma("unroll")                                                      \
        for (int k = 0; k < 4; ++k) {                                          \
            int slot = k * 4 + wv;                                             \
            int gi = slot >> 1, hl = slot & 1;                                 \
            const char* src = Ag + (((gi * 16) + (ktB_) + hl * 8) << 10) + laneoff; \
            gload_lds16(src, &stg[buf][k * 4096 + wv * 1024 + laneoff]);       \
        }                                                                      \
        _Pragma("unroll")                                                      \
        for (int k = 0; k < 4; ++k) {                                          \
            int slot = k * 4 + wv;                                             \
            const char* src = Bg + ((slot * 8 + (ktB_)) << 10) + laneoff;      \
            gload_lds16(src, &stg[buf][16384 + k * 4096 + wv * 1024 + laneoff]); \
        }                                                                      \
    }

    floatx4 acc[4][8];
#pragma unroll
    for (int i = 0; i < 4; ++i)
#pragma unroll
        for (int j = 0; j < 8; ++j) acc[i][j] = (floatx4)0.f;

    STAGE_CHUNK(0, 0);
    __syncthreads();                       // drains stage 0 (vmcnt(0))

    for (int ktB = 0; ktB < 8; ++ktB) {
        int cur = ktB & 1;
        if (ktB < 7) STAGE_CHUNK(cur ^ 1, ktB + 1);
        const char* sb = &stg[cur][0];
        short8 ah[4], al[4], bf[8];
#pragma unroll
        for (int j = 0; j < 8; ++j)
            bf[j] = *(const short8*)(sb + 16384 + ((wn * 8 + j) << 10) + laneoff);
#pragma unroll
        for (int i = 0; i < 4; ++i) {
            ah[i] = *(const short8*)(sb + (((wm * 4 + i) * 2 + 0) << 10) + laneoff);
            al[i] = *(const short8*)(sb + (((wm * 4 + i) * 2 + 1) << 10) + laneoff);
        }
#pragma unroll
        for (int i = 0; i < 4; ++i)
#pragma unroll
            for (int j = 0; j < 8; ++j)
                acc[i][j] = __builtin_amdgcn_mfma_f32_16x16x32_bf16(
                    ah[i], bf[j], acc[i][j], 0, 0, 0);
#pragma unroll
        for (int i = 0; i < 4; ++i)
#pragma unroll
            for (int j = 0; j < 8; ++j)
                acc[i][j] = __builtin_amdgcn_mfma_f32_16x16x32_bf16(
                    al[i], bf[j], acc[i][j], 0, 0, 0);
        __syncthreads();   // all waves done reading cur; next stage drained
    }

    // epilogue: spikes into LDS (sp aliases stg); borderline -> rescue staging
    unsigned char* sp = (unsigned char*)&stg[0][0];   // 128*264 = 33792 <= 65536
#pragma unroll
    for (int i = 0; i < 4; ++i) {
#pragma unroll
        for (int j = 0; j < 8; ++j) {
            int cb = wn * 128 + j * 16 + lm;
            int cg = p * 256 + cb;
            float bj = bias[cg];
#pragma unroll
            for (int r = 0; r < 4; ++r) {
                int s = wm * 64 + i * 16 + lq * 4 + r;
                float v = acc[i][j][r] + bj;
                if (fabsf(v - 2.0f) < BAND) {
                    unsigned ent = ((unsigned)mb << 17) | ((unsigned)s << 10) | (unsigned)cg;
                    unsigned slot = atomicAdd(&lcnt, 1u);
                    if (slot < RBCAP) {
                        rbuf[slot] = ent;
                    } else {                       // overflow fallback (cold)
                        unsigned gs = atomicAdd(rcnt, 1u);
                        if (gs < RCAP) rl[gs] = ent;
                    }
                }
                sp[s * 264 + cb] = (v >= 2.0f) ? 1 : 0;
            }
        }
    }
    __syncthreads();

    // bulk-reserve rescue slots: ONE global atomic per block
    unsigned cnt = lcnt;
    if (cnt > RBCAP) cnt = RBCAP;
    if (tid == 0) sbase = atomicAdd(rcnt, cnt);
    __syncthreads();
    for (unsigned e = tid; e < cnt; e += 256) {
        unsigned slot = sbase + e;
        if (slot < RCAP) rl[slot] = rbuf[e];
    }

    if (p == 0) {
        // pack q bitmasks over channel-within-head: qm[g][s][h]
        const unsigned* spw = (const unsigned*)sp;   // pitch 66 words
#pragma unroll
        for (int t = 0; t < 4; ++t) {
            int w = t * 256 + tid;
            int s = w >> 3, h = w & 7;
            unsigned m = 0;
#pragma unroll
            for (int q = 0; q < 8; ++q)
                m |= p4(spw[s * 66 + h * 8 + q]) << (q * 4);
            qm[(size_t)mb * 1024 + w] = m;
        }
    } else {
        // pack k/v bitmasks along s: (kb|vb)[(mb*256+c)*4 + w2]
        unsigned wrd[4];
#pragma unroll
        for (int w2 = 0; w2 < 4; ++w2) {
            unsigned m = 0;
#pragma unroll
            for (int ii = 0; ii < 32; ++ii)
                m |= (unsigned)(sp[(w2 * 32 + ii) * 264 + tid] & 1) << ii;
            wrd[w2] = m;
        }
        uint4 o; o.x = wrd[0]; o.y = wrd[1]; o.z = wrd[2]; o.w = wrd[3];
        *(uint4*)(((p == 1) ? kb : vb) + ((size_t)mb * 256 + tid) * 4) = o;
    }
}

// ---- rescue: LANE-PARALLEL serial ascending-k fp32 FMA per entry.
// Per-entry summation order identical to the validated serial rescue.
__global__ __launch_bounds__(256) void rescue_fix(const float* __restrict__ x,
        const float* __restrict__ W, const float* __restrict__ bias,
        const unsigned* __restrict__ rl, const unsigned* __restrict__ rcnt,
        unsigned* __restrict__ qm, unsigned* __restrict__ kb,
        unsigned* __restrict__ vb) {
    unsigned n = *rcnt; if (n > RCAP) n = RCAP;
    unsigned gid = blockIdx.x * 256 + threadIdx.x;
    unsigned stride = gridDim.x * 256;
    for (unsigned e = gid; e < n; e += stride) {
        unsigned ent = rl[e];
        int mb = ent >> 17, s = (ent >> 10) & 127, cg = ent & 1023;
        const float* ar = x + xoff_row(mb, s);
        const float* wc = W + cg;
        float da = 0.f;
#pragma unroll 4
        for (int k4 = 0; k4 < 64; ++k4) {
            float4 a4 = *(const float4*)(ar + k4 * 4);
            da = fmaf(a4.x, wc[(size_t)(k4 * 4 + 0) * NC3], da);
            da = fmaf(a4.y, wc[(size_t)(k4 * 4 + 1) * NC3], da);
            da = fmaf(a4.z, wc[(size_t)(k4 * 4 + 2) * NC3], da);
            da = fmaf(a4.w, wc[(size_t)(k4 * 4 + 3) * NC3], da);
        }
        da += bias[cg];
        int spk = (da >= 2.0f) ? 1 : 0;
        if (cg < 256) {
            int h = cg >> 5, d = cg & 31;
            unsigned* wp = qm + (size_t)mb * 1024 + s * 8 + h;
            unsigned bit = 1u << d;
            int have = (*wp & bit) ? 1 : 0;
            if (have != spk) atomicXor(wp, bit);
        } else {
            unsigned* tgt = (cg < 512) ? kb : vb;
            int c = cg & 255;
            unsigned* wp = tgt + ((size_t)mb * 256 + c) * 4 + (s >> 5);
            unsigned bit = 1u << (s & 31);
            int have = (*wp & bit) ? 1 : 0;
            if (have != spk) atomicXor(wp, bit);
        }
    }
}

// ---- K3.5: column sums of k spikes from bitmasks ----
__global__ __launch_bounds__(256) void kcs_bits(const unsigned* __restrict__ kb,
                                                float* __restrict__ kcs) {
    int g = blockIdx.x;
    int c = threadIdx.x;
    const unsigned* p = kb + ((size_t)g * 256 + c) * 4;
    int acc = __popc(p[0]) + __popc(p[1]) + __popc(p[2]) + __popc(p[3]);
    kcs[g * C_ + c] = (float)acc;
}

// ---- K4: kv[g,h,d,e] = popcount over gathered s-bitmasks (exact int) ----
__global__ __launch_bounds__(256) void kv_bits(const unsigned* __restrict__ kb,
        const unsigned* __restrict__ vb, const int* __restrict__ idx,
        float* __restrict__ kvbuf) {
    int g = blockIdx.x;            // 512
    int tb = g >> 6, n = g & 63, b = tb & 1;
    int tid = threadIdx.x;
    __shared__ uint4 kbl[1024];
    __shared__ uint4 vbl[1024];
    __shared__ int widx[TOPK_];
    if (tid < TOPK_) widx[tid] = idx[(b * 64 + n) * TOPK_ + tid];
    __syncthreads();
#pragma unroll
    for (int kk = 0; kk < TOPK_; ++kk) {
        int g2 = tb * 64 + widx[kk];
        kbl[kk * 256 + tid] = *(const uint4*)&kb[((size_t)g2 * 256 + tid) * 4];
        vbl[kk * 256 + tid] = *(const uint4*)&vb[((size_t)g2 * 256 + tid) * 4];
    }
    __syncthreads();
    int h = tid >> 5, e = tid & 31;
    uint4 vw0 = vbl[0 * 256 + h * 32 + e];
    uint4 vw1 = vbl[1 * 256 + h * 32 + e];
    uint4 vw2 = vbl[2 * 256 + h * 32 + e];
    uint4 vw3 = vbl[3 * 256 + h * 32 + e];
    for (int d = 0; d < 32; ++d) {
        uint4 k0 = kbl[0 * 256 + h * 32 + d];
        uint4 k1 = kbl[1 * 256 + h * 32 + d];
        uint4 k2 = kbl[2 * 256 + h * 32 + d];
        uint4 k3 = kbl[3 * 256 + h * 32 + d];
        int acc = __popc(k0.x & vw0.x) + __popc(k0.y & vw0.y)
                + __popc(k0.z & vw0.z) + __popc(k0.w & vw0.w)
                + __popc(k1.x & vw1.x) + __popc(k1.y & vw1.y)
                + __popc(k1.z & vw1.z) + __popc(k1.w & vw1.w)
                + __popc(k2.x & vw2.x) + __popc(k2.y & vw2.y)
                + __popc(k2.z & vw2.z) + __popc(k2.w & vw2.w)
                + __popc(k3.x & vw3.x) + __popc(k3.y & vw3.y)
                + __popc(k3.z & vw3.z) + __popc(k3.w & vw3.w);
        kvbuf[((size_t)(g * 8 + h) * 32 + d) * 32 + e] = (float)acc;
    }
}

// ---- K5: FUSED attn + proj. One block = 32 rows of one window g. ----
// (Validated 2048-block structure.)
__global__ __launch_bounds__(256) void attn_proj(const unsigned* __restrict__ qm,
        const float* __restrict__ kvbuf, const float* __restrict__ kcs,
        const int* __restrict__ idx, const short* __restrict__ Bp,
        const float* __restrict__ bias, float* __restrict__ out) {
    __shared__ __align__(16) short aw[16384];   // 32 KB frags; reused as float ow[32][256]
    __shared__ unsigned qb[256];
    __shared__ float ksl[256];
    __shared__ int widx[TOPK_];
    const int bid = blockIdx.x;        // 2048
    const int g = bid >> 2, qr = bid & 3;
    const int tb = g >> 6, n = g & 63, b = tb & 1;
    const int tid = threadIdx.x;
    if (tid < TOPK_) widx[tid] = idx[(b * 64 + n) * TOPK_ + tid];
    __syncthreads();
    float ks = 0.f;
#pragma unroll
    for (int kk = 0; kk < TOPK_; ++kk)
        ks += kcs[(size_t)(tb * 64 + widx[kk]) * C_ + tid];
    ksl[tid] = ks;
    qb[tid] = qm[(size_t)g * 1024 + qr * 256 + tid];
    __syncthreads();

    const int h = tid >> 5, e = tid & 31;
    float kvr[32], ksr[32];
#pragma unroll
    for (int d = 0; d < 32; ++d)
        kvr[d] = kvbuf[((size_t)(g * 8 + h) * 32 + d) * 32 + e];
#pragma unroll
    for (int d = 0; d < 32; ++d) ksr[d] = ksl[h * 32 + d];

    const int ktAh = tid >> 5, ktAl = 8 + (tid >> 5);
    const int octsh = ((tid >> 3) & 3) << 4, sub = tid & 7;
    for (int sl = 0; sl < 32; ++sl) {
        unsigned qw = qb[sl * 8 + h];
        float r;
        if (qw == 0u) {
            r = 0.f;
        } else {
            float num = 0.f, den = 0.f;
#pragma unroll
            for (int d = 0; d < 32; ++d) {
                float m = (float)((qw >> d) & 1u);
                num = fmaf(m, kvr[d], num);
                den = fmaf(m, ksr[d], den);
            }
            r = num / (den + 1e-6f);
        }
        short hi = f2bf(r), lo = f2bf(r - bf2f(hi));
        int lane2 = (sl & 15) | octsh;
        int gi = sl >> 4;
        aw[((gi * 16 + ktAh) * 64 + lane2) * 8 + sub] = hi;
        aw[((gi * 16 + ktAl) * 64 + lane2) * 8 + sub] = lo;
    }
    __syncthreads();

    // proj: M=32, N=256; 4 waves each N=64
    const int wvw = tid >> 6, lane = tid & 63;
    const int lm = lane & 15, lq = lane >> 4;
    floatx4 pacc[2][4];
#pragma unroll
    for (int i = 0; i < 2; ++i)
#pragma unroll
        for (int j = 0; j < 4; ++j) pacc[i][j] = (floatx4)0.f;
    const short* Bb = Bp + ((size_t)(wvw * 4) * 24) * 512 + lane * 8;
#pragma unroll 2
    for (int kt = 0; kt < 24; ++kt) {
        int ktA = (kt < 16) ? kt : kt - 16;
        short8 af[2], bf[4];
#pragma unroll
        for (int i = 0; i < 2; ++i)
            af[i] = *(const short8*)&aw[((i * 16 + ktA) * 64 + lane) * 8];
#pragma unroll
        for (int j = 0; j < 4; ++j)
            bf[j] = *(const short8*)(Bb + (size_t)(j * 24 + kt) * 512);
#pragma unroll
        for (int i = 0; i < 2; ++i)
#pragma unroll
            for (int j = 0; j < 4; ++j)
                pacc[i][j] = __builtin_amdgcn_mfma_f32_16x16x32_bf16(
                    af[i], bf[j], pacc[i][j], 0, 0, 0);
    }
    __syncthreads();

    float* ow = (float*)aw;            // 32 x 256 fp32 rows
#pragma unroll
    for (int i = 0; i < 2; ++i) {
#pragma unroll
        for (int j = 0; j < 4; ++j) {
            int c = wvw * 64 + j * 16 + lm;
            float bj = bias[c];
#pragma unroll
            for (int r = 0; r < 4; ++r)
                ow[(i * 16 + lq * 4 + r) * 256 + c] = pacc[i][j][r] + bj;
        }
    }
    __syncthreads();

    // coalesced un-windowize store: rows are contiguous 1 KB in out
    int sl2 = tid >> 3, pc = (tid & 7) * 32;
    int off = xoff_row(g, qr * 32 + sl2) + pc;
#pragma unroll
    for (int q = 0; q < 8; ++q)
        *(float4*)(out + off + q * 4) = *(const float4*)&ow[sl2 * 256 + pc + q * 4];
}

extern "C" void kernel_launch(void* const* d_in, const int* in_sizes, int n_in,
                              void* d_out, int out_size, void* d_ws, size_t ws_size,
                              hipStream_t stream) {
    (void)in_sizes; (void)n_in; (void)out_size; (void)ws_size;
    const float* x    = (const float*)d_in[0];
    const float* Wqkv = (const float*)d_in[1];
    const float* bqkv = (const float*)d_in[2];
    const float* Wp   = (const float*)d_in[3];
    const float* bp   = (const float*)d_in[4];
    char* ws = (char*)d_ws;
    short*    A2    = (short*)   (ws + OFF_A2);
    short*    Bq    = (short*)   (ws + OFF_BQ);
    short*    Bpj   = (short*)   (ws + OFF_BP);
    unsigned* qmv   = (unsigned*)(ws + OFF_QM);
    unsigned* kb    = (unsigned*)(ws + OFF_KB);
    unsigned* vb    = (unsigned*)(ws + OFF_VB);
    float*    kvbuf = (float*)   (ws + OFF_KV);
    float*    kcs   = (float*)   (ws + OFF_KCS);
    float*    part  = (float*)   (ws + OFF_PART);
    float*    region= (float*)   (ws + OFF_REGION);
    int*      idxb  = (int*)     (ws + OFF_IDX);
    unsigned* rl    = (unsigned*)(ws + OFF_RL);
    unsigned* rcnt  = (unsigned*)(ws + OFF_RC);
    float*    out   = (float*)d_out;

    hipMemsetAsync(rcnt, 0, 4, stream);
    b_build_qkv    <<<dim3(256, 3), 256, 0, stream>>>(Wqkv, Bq);
    b_build_proj   <<<768, 256, 0, stream>>>(Wp, Bpj);
    k_partial_split<<<512, 256, 0, stream>>>(x, part, A2);
    k_region       <<<128, 256, 0, stream>>>(part, region);
    k_scores       <<<128,  64, 0, stream>>>(region, idxb);
    qkv_mfma       <<<1536, 256, 0, stream>>>(A2, Bq, bqkv, qmv, kb, vb, rl, rcnt);
    rescue_fix     <<<256, 256, 0, stream>>>(x, Wqkv, bqkv, rl, rcnt, qmv, kb, vb);
    kcs_bits       <<<512, 256, 0, stream>>>(kb, kcs);
    kv_bits        <<<512, 256, 0, stream>>>(kb, vb, idxb, kvbuf);
    attn_proj      <<<2048, 256, 0, stream>>>(qmv, kvbuf, kcs, idxb, Bpj, bp, out);
}